// Round 1
// baseline (1992.474 us; speedup 1.0000x reference)
//
#include <hip/hip_runtime.h>
#include <stdint.h>

// ---------------------------------------------------------------------------
// EideticPhysicsAttention: N=65536 tokens, HID=512, H=8 heads, D=64, G=64.
// Pipeline:
//   K1  gemm_nt_bias : xp = x @ W_x.T + b_x            (xp stored in d_out)
//   K2  k2_route     : per (h,n): temp MLP, logits, threefry-gumbel, softmax
//                      -> w_cat[n][h*64+g]  (134 MB in ws)
//   K3  k3_pool      : tok_num[h,g,d] = sum_n x_mid*w ; norm[h,g] = sum_n w
//   K4a k4_attn      : per-head 64-token attention -> o[h,g,d]
//   K4b k4b_m2       : M2T[j][hg] = sum_d o[hg][d] * W_out[j][h*64+d]
//   K5  gemm_nt_bias : out = w_cat @ M2T.T + b_out     (overwrites d_out)
// ---------------------------------------------------------------------------

__device__ __forceinline__ float gelu_f(float x) {
  // jax.nn.gelu approximate=True: 0.5*x*(1+tanh(sqrt(2/pi)*(x+0.044715*x^3)))
  const float c = 0.79788456080286535588f;
  float x3 = x * x * x;
  float inner = c * fmaf(0.044715f, x3, x);
  return 0.5f * x * (1.0f + tanhf(inner));
}

__device__ __forceinline__ uint32_t rotl32(uint32_t v, int s) {
  return (v << s) | (v >> (32 - s));
}

// JAX threefry2x32, key = (0,1) from jax.random.key(1), partitionable path:
// inputs (hi, lo) = (0, idx); 32-bit draw returns out0 ^ out1.
__device__ __forceinline__ uint32_t threefry_bits(uint32_t idx) {
  const uint32_t k0 = 0u, k1 = 1u;
  const uint32_t k2 = 0x1BD11BDAu ^ k0 ^ k1;  // 0x1BD11BDB
  uint32_t x0 = 0u + k0;
  uint32_t x1 = idx + k1;
#define TF_R(r) { x0 += x1; x1 = rotl32(x1, r); x1 ^= x0; }
  TF_R(13) TF_R(15) TF_R(26) TF_R(6)
  x0 += k1; x1 += k2 + 1u;
  TF_R(17) TF_R(29) TF_R(16) TF_R(24)
  x0 += k2; x1 += k0 + 2u;
  TF_R(13) TF_R(15) TF_R(26) TF_R(6)
  x0 += k0; x1 += k1 + 3u;
  TF_R(17) TF_R(29) TF_R(16) TF_R(24)
  x0 += k1; x1 += k2 + 4u;
  TF_R(13) TF_R(15) TF_R(26) TF_R(6)
  x0 += k2; x1 += k0 + 5u;
#undef TF_R
  return x0 ^ x1;
}

// ---------------------------------------------------------------------------
// Generic f32 GEMM (NT): C[m][j] = sum_k A[m][k]*B[j][k] + bias[j]
// M=65536, N=512, K=512. 128x128 tile, BK=8, 256 threads, 8x8 micro-tile
// (split as 2x2 blocks of 4x4 at +0/+64 to keep LDS reads 2-way max).
// ---------------------------------------------------------------------------
__global__ __launch_bounds__(256) void gemm_nt_bias(
    const float* __restrict__ A, const float* __restrict__ B,
    const float* __restrict__ bias, float* __restrict__ C)
{
  __shared__ float As[8][132];
  __shared__ float Bs[8][132];
  const int tid = threadIdx.x;
  const int bn = blockIdx.x & 3;   // 4 col tiles of 128 over N=512
  const int bm = blockIdx.x >> 2;  // 512 row tiles of 128 over M=65536
  const int tx = tid & 15, ty = tid >> 4;
  const int lrow = tid >> 1;        // 0..127
  const int lk = (tid & 1) * 4;     // 0 or 4
  const float* aptr = A + (size_t)(bm * 128 + lrow) * 512 + lk;
  const float* bptr = B + (size_t)(bn * 128 + lrow) * 512 + lk;

  float acc[8][8];
#pragma unroll
  for (int i = 0; i < 8; ++i)
#pragma unroll
    for (int j = 0; j < 8; ++j) acc[i][j] = 0.f;

  for (int k0 = 0; k0 < 512; k0 += 8) {
    float4 av = *(const float4*)(aptr + k0);
    float4 bv = *(const float4*)(bptr + k0);
    __syncthreads();
    As[lk + 0][lrow] = av.x; As[lk + 1][lrow] = av.y;
    As[lk + 2][lrow] = av.z; As[lk + 3][lrow] = av.w;
    Bs[lk + 0][lrow] = bv.x; Bs[lk + 1][lrow] = bv.y;
    Bs[lk + 2][lrow] = bv.z; Bs[lk + 3][lrow] = bv.w;
    __syncthreads();
#pragma unroll
    for (int kk = 0; kk < 8; ++kk) {
      float4 a0 = *(const float4*)&As[kk][ty * 4];
      float4 a1 = *(const float4*)&As[kk][64 + ty * 4];
      float4 b0 = *(const float4*)&Bs[kk][tx * 4];
      float4 b1 = *(const float4*)&Bs[kk][64 + tx * 4];
      float ar[8] = {a0.x, a0.y, a0.z, a0.w, a1.x, a1.y, a1.z, a1.w};
      float br[8] = {b0.x, b0.y, b0.z, b0.w, b1.x, b1.y, b1.z, b1.w};
#pragma unroll
      for (int i = 0; i < 8; ++i)
#pragma unroll
        for (int j = 0; j < 8; ++j)
          acc[i][j] = fmaf(ar[i], br[j], acc[i][j]);
    }
  }

#pragma unroll
  for (int i = 0; i < 8; ++i) {
    const int m = bm * 128 + (i >> 2) * 64 + ty * 4 + (i & 3);
#pragma unroll
    for (int jb = 0; jb < 2; ++jb) {
      const int c0 = bn * 128 + jb * 64 + tx * 4;
      float4 o;
      o.x = acc[i][jb * 4 + 0] + bias[c0 + 0];
      o.y = acc[i][jb * 4 + 1] + bias[c0 + 1];
      o.z = acc[i][jb * 4 + 2] + bias[c0 + 2];
      o.w = acc[i][jb * 4 + 3] + bias[c0 + 3];
      *(float4*)(C + (size_t)m * 512 + c0) = o;
    }
  }
}

// ---------------------------------------------------------------------------
// K2: one wave per (h,n) pair, 16 pairs per wave, 4 waves per block.
// lane = g. Weight rows W_slice[g,:], W_t1[g,:] cached in registers.
// ---------------------------------------------------------------------------
__global__ __launch_bounds__(256) void k2_route(
    const float* __restrict__ xp, const float* __restrict__ Wslice,
    const float* __restrict__ bslice, const float* __restrict__ Wt1,
    const float* __restrict__ bt1, const float* __restrict__ Wt2,
    const float* __restrict__ bt2, const float* __restrict__ tbias,
    float* __restrict__ wout)
{
  const int lane = threadIdx.x & 63;
  const int wid = threadIdx.x >> 6;

  float ws[64], wt[64];
#pragma unroll
  for (int k = 0; k < 16; ++k) {
    float4 a = *(const float4*)&Wslice[lane * 64 + k * 4];
    float4 b = *(const float4*)&Wt1[lane * 64 + k * 4];
    ws[k * 4 + 0] = a.x; ws[k * 4 + 1] = a.y; ws[k * 4 + 2] = a.z; ws[k * 4 + 3] = a.w;
    wt[k * 4 + 0] = b.x; wt[k * 4 + 1] = b.y; wt[k * 4 + 2] = b.z; wt[k * 4 + 3] = b.w;
  }
  const float wt2v = Wt2[lane];
  const float bsl  = bslice[lane];
  const float bt1v = bt1[lane];
  const float bt2v = bt2[0];

  const int TOK = 16;
  const int pbase = (blockIdx.x * 4 + wid) * TOK;
  for (int i = 0; i < TOK; ++i) {
    const int p = pbase + i;
    const int h = p >> 16;
    const int n = p & 65535;
    const float xv = xp[(size_t)n * 512 + h * 64 + lane];

    float logit = bsl, t1 = bt1v;
#pragma unroll
    for (int d = 0; d < 64; ++d) {
      const float bx = __shfl(xv, d);
      logit = fmaf(bx, ws[d], logit);
      t1 = fmaf(bx, wt[d], t1);
    }

    // temperature: gelu -> dot(G) -> gelu -> +bias -> clip(min=0.01)
    float tc = gelu_f(t1) * wt2v;
#pragma unroll
    for (int m = 32; m >= 1; m >>= 1) tc += __shfl_xor(tc, m);
    float tval = gelu_f(tc + bt2v) + tbias[h];
    tval = fmaxf(tval, 0.01f);

    // gumbel noise (JAX threefry, partitionable)
    const uint32_t idx = ((uint32_t)p << 6) | (uint32_t)lane;
    const uint32_t bits = threefry_bits(idx);
    float u = __uint_as_float((bits >> 9) | 0x3f800000u) - 1.0f;
    u = fmaxf(u, 0.0f);
    const float inner = -logf(u + 1e-8f);
    const float gn = -logf(inner + 1e-8f);

    // softmax over g
    const float s = (logit + gn) / tval;
    float mx = s;
#pragma unroll
    for (int m = 32; m >= 1; m >>= 1) mx = fmaxf(mx, __shfl_xor(mx, m));
    const float e = expf(s - mx);
    float se = e;
#pragma unroll
    for (int m = 32; m >= 1; m >>= 1) se += __shfl_xor(se, m);

    wout[(size_t)n * 512 + h * 64 + lane] = e / se;
  }
}

// ---------------------------------------------------------------------------
// K3: pooling. grid = 8 heads * 64 chunks (1024 tokens); wave: 256 tokens.
// lane = g holds acc[d] in registers; block-reduce in LDS; atomicAdd global.
// ---------------------------------------------------------------------------
__global__ __launch_bounds__(256) void k3_pool(
    const float* __restrict__ xp, const float* __restrict__ wcat,
    float* __restrict__ tok_num, float* __restrict__ nrm)
{
  __shared__ float red[4][64 * 65];
  __shared__ float rn[4][64];
  const int h = blockIdx.x >> 6;
  const int chunk = blockIdx.x & 63;
  const int lane = threadIdx.x & 63;
  const int wid = threadIdx.x >> 6;

  float acc[64];
#pragma unroll
  for (int d = 0; d < 64; ++d) acc[d] = 0.f;
  float nacc = 0.f;

  const int n0 = chunk * 1024 + wid * 256;
  for (int i = 0; i < 256; ++i) {
    const int n = n0 + i;
    const float xv = xp[(size_t)n * 512 + h * 64 + lane];
    const float wv = wcat[(size_t)n * 512 + h * 64 + lane];
    nacc += wv;
#pragma unroll
    for (int d = 0; d < 64; ++d)
      acc[d] = fmaf(wv, __shfl(xv, d), acc[d]);
  }

#pragma unroll
  for (int d = 0; d < 64; ++d) red[wid][lane * 65 + d] = acc[d];
  rn[wid][lane] = nacc;
  __syncthreads();

  for (int e = threadIdx.x; e < 4096; e += 256) {
    const int g = e >> 6, d = e & 63;
    const float v = red[0][g * 65 + d] + red[1][g * 65 + d] +
                    red[2][g * 65 + d] + red[3][g * 65 + d];
    atomicAdd(&tok_num[h * 4096 + e], v);
  }
  if (threadIdx.x < 64) {
    const float v = rn[0][threadIdx.x] + rn[1][threadIdx.x] +
                    rn[2][threadIdx.x] + rn[3][threadIdx.x];
    atomicAdd(&nrm[h * 64 + threadIdx.x], v);
  }
}

// ---------------------------------------------------------------------------
// K4a: per-head attention over G=64 slice tokens. One block per head.
// ---------------------------------------------------------------------------
__global__ __launch_bounds__(256) void k4_attn(
    const float* __restrict__ tok_num, const float* __restrict__ nrm,
    const float* __restrict__ Wq, const float* __restrict__ Wk,
    const float* __restrict__ Wv, const float* __restrict__ Wo,
    float* __restrict__ o_out)
{
  __shared__ float T[64][65], Abuf[64][65], Bbuf[64][65], Wbuf[64][65], S2[64][65];
  const int h = blockIdx.x;
  const int tid = threadIdx.x;

  for (int e = tid; e < 4096; e += 256) {
    const int g = e >> 6, d = e & 63;
    T[g][d] = tok_num[h * 4096 + e] / (nrm[h * 64 + g] + 1e-5f);
  }
  for (int e = tid; e < 4096; e += 256) Wbuf[e >> 6][e & 63] = Wq[e];
  __syncthreads();

  const int g = tid >> 2, d0 = (tid & 3) * 16;
  float r[16];

  // Q = T @ Wq.T -> Abuf
#pragma unroll
  for (int j = 0; j < 16; ++j) r[j] = 0.f;
  for (int e = 0; e < 64; ++e) {
    const float tv = T[g][e];
#pragma unroll
    for (int j = 0; j < 16; ++j) r[j] = fmaf(tv, Wbuf[d0 + j][e], r[j]);
  }
#pragma unroll
  for (int j = 0; j < 16; ++j) Abuf[g][d0 + j] = r[j];
  __syncthreads();

  for (int e = tid; e < 4096; e += 256) Wbuf[e >> 6][e & 63] = Wk[e];
  __syncthreads();

  // K = T @ Wk.T -> Bbuf
#pragma unroll
  for (int j = 0; j < 16; ++j) r[j] = 0.f;
  for (int e = 0; e < 64; ++e) {
    const float tv = T[g][e];
#pragma unroll
    for (int j = 0; j < 16; ++j) r[j] = fmaf(tv, Wbuf[d0 + j][e], r[j]);
  }
#pragma unroll
  for (int j = 0; j < 16; ++j) Bbuf[g][d0 + j] = r[j];
  __syncthreads();

  // scores S2[g][j] = sum_d (Q[g][d]*0.125) * K[j][d]
#pragma unroll
  for (int j = 0; j < 16; ++j) r[j] = 0.f;
  for (int e = 0; e < 64; ++e) {
    const float qv = Abuf[g][e] * 0.125f;
#pragma unroll
    for (int j = 0; j < 16; ++j) r[j] = fmaf(qv, Bbuf[d0 + j][e], r[j]);
  }
#pragma unroll
  for (int j = 0; j < 16; ++j) S2[g][d0 + j] = r[j];
  __syncthreads();

  // row softmax
  if (tid < 64) {
    float mx = -1e30f;
    for (int j = 0; j < 64; ++j) mx = fmaxf(mx, S2[tid][j]);
    float sum = 0.f;
    for (int j = 0; j < 64; ++j) {
      const float e2 = expf(S2[tid][j] - mx);
      S2[tid][j] = e2;
      sum += e2;
    }
    const float inv = 1.0f / sum;
    for (int j = 0; j < 64; ++j) S2[tid][j] *= inv;
  }
  __syncthreads();

  for (int e = tid; e < 4096; e += 256) Wbuf[e >> 6][e & 63] = Wv[e];
  __syncthreads();

  // V = T @ Wv.T -> Bbuf (K dead)
#pragma unroll
  for (int j = 0; j < 16; ++j) r[j] = 0.f;
  for (int e = 0; e < 64; ++e) {
    const float tv = T[g][e];
#pragma unroll
    for (int j = 0; j < 16; ++j) r[j] = fmaf(tv, Wbuf[d0 + j][e], r[j]);
  }
  __syncthreads();
#pragma unroll
  for (int j = 0; j < 16; ++j) Bbuf[g][d0 + j] = r[j];
  __syncthreads();

  // o1 = S2 @ V -> Abuf (Q dead)
#pragma unroll
  for (int j = 0; j < 16; ++j) r[j] = 0.f;
  for (int e = 0; e < 64; ++e) {
    const float sv = S2[g][e];
#pragma unroll
    for (int j = 0; j < 16; ++j) r[j] = fmaf(sv, Bbuf[e][d0 + j], r[j]);
  }
  __syncthreads();
#pragma unroll
  for (int j = 0; j < 16; ++j) Abuf[g][d0 + j] = r[j];
  for (int e = tid; e < 4096; e += 256) Wbuf[e >> 6][e & 63] = Wo[e];
  __syncthreads();

  // o = o1 @ Wo.T -> global
#pragma unroll
  for (int j = 0; j < 16; ++j) r[j] = 0.f;
  for (int e = 0; e < 64; ++e) {
    const float ov = Abuf[g][e];
#pragma unroll
    for (int j = 0; j < 16; ++j) r[j] = fmaf(ov, Wbuf[d0 + j][e], r[j]);
  }
#pragma unroll
  for (int j = 0; j < 16; ++j) o_out[h * 4096 + g * 64 + d0 + j] = r[j];
}

// ---------------------------------------------------------------------------
// K4b: M2T[j][hg] = sum_d o[hg][d] * W_out[j][ (hg>>6)*64 + d ]
// ---------------------------------------------------------------------------
__global__ __launch_bounds__(256) void k4b_m2(
    const float* __restrict__ o, const float* __restrict__ Wout,
    float* __restrict__ M2T)
{
  const int j = blockIdx.x >> 1;
  const int hg = ((blockIdx.x & 1) << 8) + threadIdx.x;
  const int h = hg >> 6;
  const float* orow = &o[hg * 64];
  const float* wrow = &Wout[j * 512 + h * 64];
  float s = 0.f;
#pragma unroll
  for (int d = 0; d < 64; ++d) s = fmaf(orow[d], wrow[d], s);
  M2T[j * 512 + hg] = s;
}

// ---------------------------------------------------------------------------
extern "C" void kernel_launch(void* const* d_in, const int* in_sizes, int n_in,
                              void* d_out, int out_size, void* d_ws, size_t ws_size,
                              hipStream_t stream)
{
  const float* x      = (const float*)d_in[0];
  const float* W_x    = (const float*)d_in[1];
  const float* b_x    = (const float*)d_in[2];
  const float* W_sl   = (const float*)d_in[3];
  const float* b_sl   = (const float*)d_in[4];
  const float* W_t1   = (const float*)d_in[5];
  const float* b_t1   = (const float*)d_in[6];
  const float* W_t2   = (const float*)d_in[7];
  const float* b_t2   = (const float*)d_in[8];
  const float* t_bias = (const float*)d_in[9];
  const float* Wq     = (const float*)d_in[10];
  const float* Wk     = (const float*)d_in[11];
  const float* Wv     = (const float*)d_in[12];
  const float* Wo     = (const float*)d_in[13];
  const float* W_out  = (const float*)d_in[14];
  const float* b_out  = (const float*)d_in[15];

  float* out = (float*)d_out;
  float* xp = out;  // xp lives in d_out; overwritten by the final GEMM

  char* ws = (char*)d_ws;
  float* wcat    = (float*)(ws);                  // 33554432 f32 = 134217728 B
  float* tok_num = (float*)(ws + 134217728);      // 32768 f32
  float* nrm     = (float*)(ws + 134348800);      // 512 f32
  float* o_buf   = (float*)(ws + 134350848);      // 32768 f32
  float* M2T     = (float*)(ws + 134481920);      // 262144 f32

  hipMemsetAsync(tok_num, 0, (32768 + 512) * sizeof(float), stream);

  gemm_nt_bias<<<2048, 256, 0, stream>>>(x, W_x, b_x, xp);
  k2_route<<<8192, 256, 0, stream>>>(xp, W_sl, b_sl, W_t1, b_t1, W_t2, b_t2,
                                     t_bias, wcat);
  k3_pool<<<512, 256, 0, stream>>>(xp, wcat, tok_num, nrm);
  k4_attn<<<8, 256, 0, stream>>>(tok_num, nrm, Wq, Wk, Wv, Wo, o_buf);
  k4b_m2<<<1024, 256, 0, stream>>>(o_buf, W_out, M2T);
  gemm_nt_bias<<<2048, 256, 0, stream>>>(wcat, M2T, b_out, out);
}

// Round 2
// 1441.777 us; speedup vs baseline: 1.3820x; 1.3820x over previous
//
#include <hip/hip_runtime.h>
#include <stdint.h>

// ---------------------------------------------------------------------------
// EideticPhysicsAttention: N=65536 tokens, HID=512, H=8 heads, D=64, G=64.
//   K1  gemm_nt_bias : xp = x @ W_x.T + b_x            (xp stored in d_out)
//   K2  k2_route     : lane=token layout; temp MLP, logits, threefry-gumbel,
//                      per-lane softmax -> wcat ; also accumulates nrm[h,g]
//   K3  k3_pool      : tok_num[h,g,d] = sum_n x_mid*w  (tiled outer product)
//   K4a k4_attn      : per-head 64-token attention -> o[h,g,d]
//   K4b k4b_m2       : M2T[j][hg] = sum_d o[hg][d] * W_out[j][h*64+d]
//   K5  gemm_nt_bias : out = wcat @ M2T.T + b_out      (overwrites d_out)
// ---------------------------------------------------------------------------

__device__ __forceinline__ float gelu_fast(float x) {
  // 0.5*x*(1+tanh(z)) == x / (1 + exp(-2z)),  z = c*(x + 0.044715 x^3)
  const float c = 0.79788456080286535588f;
  float z = c * fmaf(0.044715f, x * x * x, x);
  return x / (1.0f + __expf(-2.0f * z));
}

__device__ __forceinline__ uint32_t rotl32(uint32_t v, int s) {
  return (v << s) | (v >> (32 - s));
}

// JAX threefry2x32, key = (0,1) from jax.random.key(1), partitionable path:
// inputs (hi, lo) = (0, idx); 32-bit draw returns out0 ^ out1.  (bit-exact)
__device__ __forceinline__ uint32_t threefry_bits(uint32_t idx) {
  const uint32_t k0 = 0u, k1 = 1u;
  const uint32_t k2 = 0x1BD11BDAu ^ k0 ^ k1;  // 0x1BD11BDB
  uint32_t x0 = 0u + k0;
  uint32_t x1 = idx + k1;
#define TF_R(r) { x0 += x1; x1 = rotl32(x1, r); x1 ^= x0; }
  TF_R(13) TF_R(15) TF_R(26) TF_R(6)
  x0 += k1; x1 += k2 + 1u;
  TF_R(17) TF_R(29) TF_R(16) TF_R(24)
  x0 += k2; x1 += k0 + 2u;
  TF_R(13) TF_R(15) TF_R(26) TF_R(6)
  x0 += k0; x1 += k1 + 3u;
  TF_R(17) TF_R(29) TF_R(16) TF_R(24)
  x0 += k1; x1 += k2 + 4u;
  TF_R(13) TF_R(15) TF_R(26) TF_R(6)
  x0 += k2; x1 += k0 + 5u;
#undef TF_R
  return x0 ^ x1;
}

// ---------------------------------------------------------------------------
// Generic f32 GEMM (NT): C[m][j] = sum_k A[m][k]*B[j][k] + bias[j]
// M=65536, N=512, K=512. 128x128 tile, BK=8, 256 threads, 8x8 micro-tile.
// ---------------------------------------------------------------------------
__global__ __launch_bounds__(256) void gemm_nt_bias(
    const float* __restrict__ A, const float* __restrict__ B,
    const float* __restrict__ bias, float* __restrict__ C)
{
  __shared__ float As[8][132];
  __shared__ float Bs[8][132];
  const int tid = threadIdx.x;
  const int bn = blockIdx.x & 3;
  const int bm = blockIdx.x >> 2;
  const int tx = tid & 15, ty = tid >> 4;
  const int lrow = tid >> 1;
  const int lk = (tid & 1) * 4;
  const float* aptr = A + (size_t)(bm * 128 + lrow) * 512 + lk;
  const float* bptr = B + (size_t)(bn * 128 + lrow) * 512 + lk;

  float acc[8][8];
#pragma unroll
  for (int i = 0; i < 8; ++i)
#pragma unroll
    for (int j = 0; j < 8; ++j) acc[i][j] = 0.f;

  for (int k0 = 0; k0 < 512; k0 += 8) {
    float4 av = *(const float4*)(aptr + k0);
    float4 bv = *(const float4*)(bptr + k0);
    __syncthreads();
    As[lk + 0][lrow] = av.x; As[lk + 1][lrow] = av.y;
    As[lk + 2][lrow] = av.z; As[lk + 3][lrow] = av.w;
    Bs[lk + 0][lrow] = bv.x; Bs[lk + 1][lrow] = bv.y;
    Bs[lk + 2][lrow] = bv.z; Bs[lk + 3][lrow] = bv.w;
    __syncthreads();
#pragma unroll
    for (int kk = 0; kk < 8; ++kk) {
      float4 a0 = *(const float4*)&As[kk][ty * 4];
      float4 a1 = *(const float4*)&As[kk][64 + ty * 4];
      float4 b0 = *(const float4*)&Bs[kk][tx * 4];
      float4 b1 = *(const float4*)&Bs[kk][64 + tx * 4];
      float ar[8] = {a0.x, a0.y, a0.z, a0.w, a1.x, a1.y, a1.z, a1.w};
      float br[8] = {b0.x, b0.y, b0.z, b0.w, b1.x, b1.y, b1.z, b1.w};
#pragma unroll
      for (int i = 0; i < 8; ++i)
#pragma unroll
        for (int j = 0; j < 8; ++j)
          acc[i][j] = fmaf(ar[i], br[j], acc[i][j]);
    }
  }

#pragma unroll
  for (int i = 0; i < 8; ++i) {
    const int m = bm * 128 + (i >> 2) * 64 + ty * 4 + (i & 3);
#pragma unroll
    for (int jb = 0; jb < 2; ++jb) {
      const int c0 = bn * 128 + jb * 64 + tx * 4;
      float4 o;
      o.x = acc[i][jb * 4 + 0] + bias[c0 + 0];
      o.y = acc[i][jb * 4 + 1] + bias[c0 + 1];
      o.z = acc[i][jb * 4 + 2] + bias[c0 + 2];
      o.w = acc[i][jb * 4 + 3] + bias[c0 + 3];
      *(float4*)(C + (size_t)m * 512 + c0) = o;
    }
  }
}

// ---------------------------------------------------------------------------
// K2: lane = token. Each wave: 64 tokens of one head. W rows are wave-uniform
// (scalar loads). Scores staged in per-wave LDS tile; LDS-transpose store.
// Also accumulates nrm[h][g] (removed from K3).
// ---------------------------------------------------------------------------
__global__ __launch_bounds__(256) void k2_route(
    const float* __restrict__ xp, const float* __restrict__ Wsl,
    const float* __restrict__ bsl, const float* __restrict__ Wt1,
    const float* __restrict__ bt1, const float* __restrict__ Wt2,
    const float* __restrict__ bt2, const float* __restrict__ tbias,
    float* __restrict__ wout, float* __restrict__ nrm)
{
  __shared__ float sbuf[4][64 * 65];   // [wave][token*65 + g]
  __shared__ float invbuf[4][64];      // [wave][token] = 1/sum
  const int lane = threadIdx.x & 63;
  const int wid  = threadIdx.x >> 6;
  const int gw   = blockIdx.x * 4 + wid;   // 0..8191
  const int p    = gw * 64 + lane;         // (h,n) pair id
  const int h    = p >> 16;
  const int n    = p & 65535;
  const int n0   = (gw * 64) & 65535;      // first token of this wave

  // load x row (64 floats) into registers
  float x[64];
  const float* xrow = xp + (size_t)n * 512 + h * 64;
#pragma unroll
  for (int q = 0; q < 16; ++q) {
    float4 v = *(const float4*)(xrow + q * 4);
    x[q * 4 + 0] = v.x; x[q * 4 + 1] = v.y;
    x[q * 4 + 2] = v.z; x[q * 4 + 3] = v.w;
  }

  // phase A: temperature  tc = sum_g gelu(t1[g]) * Wt2[g]
  float tc = 0.f;
  for (int g = 0; g < 64; ++g) {
    const float* wr = Wt1 + g * 64;   // wave-uniform -> s_load
    float a0 = bt1[g], a1 = 0.f, a2 = 0.f, a3 = 0.f;
#pragma unroll
    for (int q = 0; q < 16; ++q) {
      float4 wv = *(const float4*)(wr + q * 4);
      a0 = fmaf(x[q * 4 + 0], wv.x, a0);
      a1 = fmaf(x[q * 4 + 1], wv.y, a1);
      a2 = fmaf(x[q * 4 + 2], wv.z, a2);
      a3 = fmaf(x[q * 4 + 3], wv.w, a3);
    }
    tc = fmaf(gelu_fast((a0 + a1) + (a2 + a3)), Wt2[g], tc);
  }
  float tval = gelu_fast(tc + bt2[0]) + tbias[h];
  tval = fmaxf(tval, 0.01f);
  const float itval = 1.0f / tval;

  // phase B1: logits + gumbel -> s (LDS), track per-token max
  float mx = -3.4e38f;
  for (int g = 0; g < 64; ++g) {
    const float* wr = Wsl + g * 64;   // wave-uniform -> s_load
    float a0 = bsl[g], a1 = 0.f, a2 = 0.f, a3 = 0.f;
#pragma unroll
    for (int q = 0; q < 16; ++q) {
      float4 wv = *(const float4*)(wr + q * 4);
      a0 = fmaf(x[q * 4 + 0], wv.x, a0);
      a1 = fmaf(x[q * 4 + 1], wv.y, a1);
      a2 = fmaf(x[q * 4 + 2], wv.z, a2);
      a3 = fmaf(x[q * 4 + 3], wv.w, a3);
    }
    const float lg = (a0 + a1) + (a2 + a3);

    const uint32_t bits = threefry_bits(((uint32_t)p << 6) | (uint32_t)g);
    const float u = __uint_as_float((bits >> 9) | 0x3f800000u) - 1.0f;
    const float gin = -__logf(u + 1e-8f);
    const float gn = -__logf(gin + 1e-8f);

    const float sv = (lg + gn) * itval;
    sbuf[wid][lane * 65 + g] = sv;
    mx = fmaxf(mx, sv);
  }

  // phase B2: exponentiate + sum (per lane = per token)
  float se = 0.f;
  for (int g = 0; g < 64; ++g) {
    const float e = __expf(sbuf[wid][lane * 65 + g] - mx);
    se += e;
    sbuf[wid][lane * 65 + g] = e;
  }
  invbuf[wid][lane] = 1.0f / se;

  // phase B3: transpose-read (lane = g), coalesced store + norm accumulation
  float nacc = 0.f;
  for (int t = 0; t < 64; ++t) {
    const float w = sbuf[wid][t * 65 + lane] * invbuf[wid][t];
    nacc += w;
    wout[(size_t)(n0 + t) * 512 + h * 64 + lane] = w;
  }
  atomicAdd(&nrm[h * 64 + lane], nacc);
}

// ---------------------------------------------------------------------------
// K3: tok_num[h,g,d] = sum_n w[n,g]*x[n,d].  Rank-K outer-product update.
// Grid = 8 heads x 32 chunks (2048 tokens each). 256 thr = 4 waves; each wave
// computes the full 64x64 tile for 16 of each 64 staged tokens (8x8/lane).
// ---------------------------------------------------------------------------
__global__ __launch_bounds__(256) void k3_pool(
    const float* __restrict__ xp, const float* __restrict__ wcat,
    float* __restrict__ tok_num)
{
  __shared__ float Xs[64][66];
  __shared__ float Ws[64][66];
  const int h = blockIdx.x >> 5;
  const int chunk = blockIdx.x & 31;
  const int tid = threadIdx.x;
  const int lane = tid & 63;
  const int wid = tid >> 6;
  const int ft = tid & 15;       // float4 index within row
  const int tk = tid >> 4;       // token 0..15 base for staging
  const int i0 = (lane & 7) * 8; // d-block
  const int j0 = (lane >> 3) * 8;// g-block

  float acc[8][8];
#pragma unroll
  for (int j = 0; j < 8; ++j)
#pragma unroll
    for (int i = 0; i < 8; ++i) acc[j][i] = 0.f;

  for (int r = 0; r < 32; ++r) {
    const int n0 = chunk * 2048 + r * 64;
    __syncthreads();
#pragma unroll
    for (int b = 0; b < 4; ++b) {
      const int t = tk + b * 16;
      const size_t off = (size_t)(n0 + t) * 512 + h * 64 + ft * 4;
      float4 xv = *(const float4*)(xp + off);
      float4 wv = *(const float4*)(wcat + off);
      *(float4*)&Xs[t][ft * 4] = xv;
      *(float4*)&Ws[t][ft * 4] = wv;
    }
    __syncthreads();
#pragma unroll 4
    for (int tt = 0; tt < 16; ++tt) {
      const int t = wid * 16 + tt;
      float x8[8], w8[8];
      *(float4*)&x8[0] = *(const float4*)&Xs[t][i0];
      *(float4*)&x8[4] = *(const float4*)&Xs[t][i0 + 4];
      *(float4*)&w8[0] = *(const float4*)&Ws[t][j0];
      *(float4*)&w8[4] = *(const float4*)&Ws[t][j0 + 4];
#pragma unroll
      for (int j = 0; j < 8; ++j)
#pragma unroll
        for (int i = 0; i < 8; ++i)
          acc[j][i] = fmaf(w8[j], x8[i], acc[j][i]);
    }
  }

#pragma unroll
  for (int j = 0; j < 8; ++j)
#pragma unroll
    for (int i = 0; i < 8; ++i)
      atomicAdd(&tok_num[h * 4096 + (j0 + j) * 64 + i0 + i], acc[j][i]);
}

// ---------------------------------------------------------------------------
// K4a: per-head attention over G=64 slice tokens. One block per head.
// ---------------------------------------------------------------------------
__global__ __launch_bounds__(256) void k4_attn(
    const float* __restrict__ tok_num, const float* __restrict__ nrm,
    const float* __restrict__ Wq, const float* __restrict__ Wk,
    const float* __restrict__ Wv, const float* __restrict__ Wo,
    float* __restrict__ o_out)
{
  __shared__ float T[64][65], Abuf[64][65], Bbuf[64][65], Wbuf[64][65], S2[64][65];
  const int h = blockIdx.x;
  const int tid = threadIdx.x;

  for (int e = tid; e < 4096; e += 256) {
    const int g = e >> 6, d = e & 63;
    T[g][d] = tok_num[h * 4096 + e] / (nrm[h * 64 + g] + 1e-5f);
  }
  for (int e = tid; e < 4096; e += 256) Wbuf[e >> 6][e & 63] = Wq[e];
  __syncthreads();

  const int g = tid >> 2, d0 = (tid & 3) * 16;
  float r[16];

#pragma unroll
  for (int j = 0; j < 16; ++j) r[j] = 0.f;
  for (int e = 0; e < 64; ++e) {
    const float tv = T[g][e];
#pragma unroll
    for (int j = 0; j < 16; ++j) r[j] = fmaf(tv, Wbuf[d0 + j][e], r[j]);
  }
#pragma unroll
  for (int j = 0; j < 16; ++j) Abuf[g][d0 + j] = r[j];
  __syncthreads();

  for (int e = tid; e < 4096; e += 256) Wbuf[e >> 6][e & 63] = Wk[e];
  __syncthreads();

#pragma unroll
  for (int j = 0; j < 16; ++j) r[j] = 0.f;
  for (int e = 0; e < 64; ++e) {
    const float tv = T[g][e];
#pragma unroll
    for (int j = 0; j < 16; ++j) r[j] = fmaf(tv, Wbuf[d0 + j][e], r[j]);
  }
#pragma unroll
  for (int j = 0; j < 16; ++j) Bbuf[g][d0 + j] = r[j];
  __syncthreads();

#pragma unroll
  for (int j = 0; j < 16; ++j) r[j] = 0.f;
  for (int e = 0; e < 64; ++e) {
    const float qv = Abuf[g][e] * 0.125f;
#pragma unroll
    for (int j = 0; j < 16; ++j) r[j] = fmaf(qv, Bbuf[d0 + j][e], r[j]);
  }
#pragma unroll
  for (int j = 0; j < 16; ++j) S2[g][d0 + j] = r[j];
  __syncthreads();

  if (tid < 64) {
    float mx = -1e30f;
    for (int j = 0; j < 64; ++j) mx = fmaxf(mx, S2[tid][j]);
    float sum = 0.f;
    for (int j = 0; j < 64; ++j) {
      const float e2 = expf(S2[tid][j] - mx);
      S2[tid][j] = e2;
      sum += e2;
    }
    const float inv = 1.0f / sum;
    for (int j = 0; j < 64; ++j) S2[tid][j] *= inv;
  }
  __syncthreads();

  for (int e = tid; e < 4096; e += 256) Wbuf[e >> 6][e & 63] = Wv[e];
  __syncthreads();

#pragma unroll
  for (int j = 0; j < 16; ++j) r[j] = 0.f;
  for (int e = 0; e < 64; ++e) {
    const float tv = T[g][e];
#pragma unroll
    for (int j = 0; j < 16; ++j) r[j] = fmaf(tv, Wbuf[d0 + j][e], r[j]);
  }
  __syncthreads();
#pragma unroll
  for (int j = 0; j < 16; ++j) Bbuf[g][d0 + j] = r[j];
  __syncthreads();

#pragma unroll
  for (int j = 0; j < 16; ++j) r[j] = 0.f;
  for (int e = 0; e < 64; ++e) {
    const float sv = S2[g][e];
#pragma unroll
    for (int j = 0; j < 16; ++j) r[j] = fmaf(sv, Bbuf[e][d0 + j], r[j]);
  }
  __syncthreads();
#pragma unroll
  for (int j = 0; j < 16; ++j) Abuf[g][d0 + j] = r[j];
  for (int e = tid; e < 4096; e += 256) Wbuf[e >> 6][e & 63] = Wo[e];
  __syncthreads();

#pragma unroll
  for (int j = 0; j < 16; ++j) r[j] = 0.f;
  for (int e = 0; e < 64; ++e) {
    const float ov = Abuf[g][e];
#pragma unroll
    for (int j = 0; j < 16; ++j) r[j] = fmaf(ov, Wbuf[d0 + j][e], r[j]);
  }
#pragma unroll
  for (int j = 0; j < 16; ++j) o_out[h * 4096 + g * 64 + d0 + j] = r[j];
}

// ---------------------------------------------------------------------------
// K4b: M2T[j][hg] = sum_d o[hg][d] * W_out[j][ (hg>>6)*64 + d ]
// ---------------------------------------------------------------------------
__global__ __launch_bounds__(256) void k4b_m2(
    const float* __restrict__ o, const float* __restrict__ Wout,
    float* __restrict__ M2T)
{
  const int j = blockIdx.x >> 1;
  const int hg = ((blockIdx.x & 1) << 8) + threadIdx.x;
  const int h = hg >> 6;
  const float* orow = &o[hg * 64];
  const float* wrow = &Wout[j * 512 + h * 64];
  float s = 0.f;
#pragma unroll
  for (int d = 0; d < 64; ++d) s = fmaf(orow[d], wrow[d], s);
  M2T[j * 512 + hg] = s;
}

// ---------------------------------------------------------------------------
extern "C" void kernel_launch(void* const* d_in, const int* in_sizes, int n_in,
                              void* d_out, int out_size, void* d_ws, size_t ws_size,
                              hipStream_t stream)
{
  const float* x      = (const float*)d_in[0];
  const float* W_x    = (const float*)d_in[1];
  const float* b_x    = (const float*)d_in[2];
  const float* W_sl   = (const float*)d_in[3];
  const float* b_sl   = (const float*)d_in[4];
  const float* W_t1   = (const float*)d_in[5];
  const float* b_t1   = (const float*)d_in[6];
  const float* W_t2   = (const float*)d_in[7];
  const float* b_t2   = (const float*)d_in[8];
  const float* t_bias = (const float*)d_in[9];
  const float* Wq     = (const float*)d_in[10];
  const float* Wk     = (const float*)d_in[11];
  const float* Wv     = (const float*)d_in[12];
  const float* Wo     = (const float*)d_in[13];
  const float* W_out  = (const float*)d_in[14];
  const float* b_out  = (const float*)d_in[15];

  float* out = (float*)d_out;
  float* xp = out;  // xp lives in d_out; overwritten by the final GEMM

  char* ws = (char*)d_ws;
  float* wcat    = (float*)(ws);                  // 33554432 f32 = 134217728 B
  float* tok_num = (float*)(ws + 134217728);      // 32768 f32
  float* nrm     = (float*)(ws + 134348800);      // 512 f32
  float* o_buf   = (float*)(ws + 134350848);      // 32768 f32
  float* M2T     = (float*)(ws + 134481920);      // 262144 f32

  hipMemsetAsync(tok_num, 0, (32768 + 512) * sizeof(float), stream);

  gemm_nt_bias<<<2048, 256, 0, stream>>>(x, W_x, b_x, xp);
  k2_route<<<2048, 256, 0, stream>>>(xp, W_sl, b_sl, W_t1, b_t1, W_t2, b_t2,
                                     t_bias, wcat, nrm);
  k3_pool<<<256, 256, 0, stream>>>(xp, wcat, tok_num);
  k4_attn<<<8, 256, 0, stream>>>(tok_num, nrm, Wq, Wk, Wv, Wo, o_buf);
  k4b_m2<<<1024, 256, 0, stream>>>(o_buf, W_out, M2T);
  gemm_nt_bias<<<2048, 256, 0, stream>>>(wcat, M2T, b_out, out);
}

// Round 3
// 931.719 us; speedup vs baseline: 2.1385x; 1.5474x over previous
//
#include <hip/hip_runtime.h>
#include <stdint.h>

typedef unsigned short u16;
typedef __bf16 bf16x8 __attribute__((ext_vector_type(8)));
typedef float f32x4 __attribute__((ext_vector_type(4)));

// ---------------------------------------------------------------------------
// EideticPhysicsAttention: N=65536 tokens, HID=512, H=8 heads, D=64, G=64.
//   conv  : split f32 -> (hi,lo) bf16 planes for x and W_x
//   K1    gemm_split : xp = x @ W_x.T + b_x   (split-bf16 MFMA, xp in d_out)
//   K2    k2_route   : temp MLP, logits, threefry-gumbel, softmax
//                      -> wcat hi/lo bf16 planes + nrm[h,g]
//   K3    k3_pool    : tok_num[h,g,d] = sum_n x_mid*w  (tiled outer product)
//   K4a   k4_attn    : per-head 64-token attention -> o[h,g,d]
//   K4b   k4b_m2     : M2T[j][hg] hi/lo = sum_d o[hg][d]*W_out[j][h*64+d]
//   K5    gemm_split : out = wcat @ M2T.T + b_out      (overwrites d_out)
// ---------------------------------------------------------------------------

__device__ __forceinline__ u16 f2bf(float f) {   // RNE bf16
  uint32_t u = __float_as_uint(f);
  uint32_t r = u + 0x7fffu + ((u >> 16) & 1u);
  return (u16)(r >> 16);
}
__device__ __forceinline__ float bf2f(u16 h) {
  return __uint_as_float(((uint32_t)h) << 16);
}

__device__ __forceinline__ float gelu_fast(float x) {
  // 0.5*x*(1+tanh(z)) == x / (1 + exp(-2z)),  z = c*(x + 0.044715 x^3)
  const float c = 0.79788456080286535588f;
  float z = c * fmaf(0.044715f, x * x * x, x);
  return x / (1.0f + __expf(-2.0f * z));
}

__device__ __forceinline__ uint32_t rotl32(uint32_t v, int s) {
  return (v << s) | (v >> (32 - s));
}

// JAX threefry2x32, key=(0,1) from jax.random.key(1), partitionable path.
__device__ __forceinline__ uint32_t threefry_bits(uint32_t idx) {
  const uint32_t k0 = 0u, k1 = 1u;
  const uint32_t k2 = 0x1BD11BDAu ^ k0 ^ k1;
  uint32_t x0 = 0u + k0;
  uint32_t x1 = idx + k1;
#define TF_R(r) { x0 += x1; x1 = rotl32(x1, r); x1 ^= x0; }
  TF_R(13) TF_R(15) TF_R(26) TF_R(6)
  x0 += k1; x1 += k2 + 1u;
  TF_R(17) TF_R(29) TF_R(16) TF_R(24)
  x0 += k2; x1 += k0 + 2u;
  TF_R(13) TF_R(15) TF_R(26) TF_R(6)
  x0 += k0; x1 += k1 + 3u;
  TF_R(17) TF_R(29) TF_R(16) TF_R(24)
  x0 += k1; x1 += k2 + 4u;
  TF_R(13) TF_R(15) TF_R(26) TF_R(6)
  x0 += k2; x1 += k0 + 5u;
#undef TF_R
  return x0 ^ x1;
}

__device__ __forceinline__ void gload_lds16(const void* g, void* l) {
  __builtin_amdgcn_global_load_lds(
      (const __attribute__((address_space(1))) void*)g,
      (__attribute__((address_space(3))) void*)l, 16, 0, 0);
}

// ---------------------------------------------------------------------------
// conv_split: f32 -> hi/lo bf16 planes (grid-stride over float4 quads)
// ---------------------------------------------------------------------------
__global__ __launch_bounds__(256) void conv_split(
    const float* __restrict__ in, u16* __restrict__ hi, u16* __restrict__ lo,
    int nq)
{
  for (int i = blockIdx.x * 256 + threadIdx.x; i < nq; i += gridDim.x * 256) {
    float4 v = ((const float4*)in)[i];
    ushort4 h, l;
    h.x = f2bf(v.x); l.x = f2bf(v.x - bf2f(h.x));
    h.y = f2bf(v.y); l.y = f2bf(v.y - bf2f(h.y));
    h.z = f2bf(v.z); l.z = f2bf(v.z - bf2f(h.z));
    h.w = f2bf(v.w); l.w = f2bf(v.w - bf2f(h.w));
    ((ushort4*)hi)[i] = h;
    ((ushort4*)lo)[i] = l;
  }
}

// ---------------------------------------------------------------------------
// gemm_split: C[m][j] = sum_k (Ah+Al)[m][k]*(Bh+Bl)[j][k] + bias[j]
// M=65536, N=512, K=512; A,B row-major [rows][512] bf16 planes.
// 128x128 tile, BK=32, 4 waves, 16x16x32 MFMA, 3 cross-term accumulation.
// ---------------------------------------------------------------------------
__global__ __launch_bounds__(256) void gemm_split(
    const u16* __restrict__ Ah, const u16* __restrict__ Al,
    const u16* __restrict__ Bh, const u16* __restrict__ Bl,
    const float* __restrict__ bias, float* __restrict__ C)
{
  __shared__ u16 lds[4][4096];   // [Ah,Al,Bh,Bl][128 rows * 32 k] = 32 KB
  const int tid = threadIdx.x;
  const int lane = tid & 63;
  const int w = tid >> 6;
  const int bn = blockIdx.x & 3;
  const int bm = blockIdx.x >> 2;
  const int wr = w >> 1, wc = w & 1;   // 2x2 wave grid, 64x64 per wave

  f32x4 acc[4][4];
#pragma unroll
  for (int m = 0; m < 4; ++m)
#pragma unroll
    for (int n = 0; n < 4; ++n) acc[m][n] = (f32x4){0.f, 0.f, 0.f, 0.f};

  const int srow = lane >> 2;        // staging row within 16-row block
  const int scol = (lane & 3) * 8;   // staging elem col (8 bf16 = 16 B)

  for (int kt = 0; kt < 16; ++kt) {
    const int k0 = kt * 32;
    __syncthreads();
#pragma unroll
    for (int i = 0; i < 8; ++i) {
      const int mat = i & 3;                 // static after unroll
      const int rb = w * 2 + (i >> 2);       // row-block 0..7
      const int row = rb * 16 + srow;
      const u16* base = (mat == 0) ? Ah : (mat == 1) ? Al
                       : (mat == 2) ? Bh : Bl;
      const int tbase = (mat < 2) ? bm * 128 : bn * 128;
      const u16* src = base + (size_t)(tbase + row) * 512 + k0 + scol;
      gload_lds16(src, &lds[mat][rb * 512]);
    }
    __syncthreads();

    bf16x8 ah[4], al[4], bh_[4], bl_[4];
    const int co = (lane >> 4) * 8;
    const int rr = lane & 15;
#pragma unroll
    for (int f = 0; f < 4; ++f) {
      const int ra  = (wr * 64 + f * 16 + rr) * 32 + co;
      const int rb2 = (wc * 64 + f * 16 + rr) * 32 + co;
      ah[f]  = *(const bf16x8*)&lds[0][ra];
      al[f]  = *(const bf16x8*)&lds[1][ra];
      bh_[f] = *(const bf16x8*)&lds[2][rb2];
      bl_[f] = *(const bf16x8*)&lds[3][rb2];
    }
#pragma unroll
    for (int m = 0; m < 4; ++m)
#pragma unroll
      for (int n = 0; n < 4; ++n) {
        acc[m][n] = __builtin_amdgcn_mfma_f32_16x16x32_bf16(ah[m], bh_[n], acc[m][n], 0, 0, 0);
        acc[m][n] = __builtin_amdgcn_mfma_f32_16x16x32_bf16(ah[m], bl_[n], acc[m][n], 0, 0, 0);
        acc[m][n] = __builtin_amdgcn_mfma_f32_16x16x32_bf16(al[m], bh_[n], acc[m][n], 0, 0, 0);
      }
  }

  // C/D layout (m89-verified): col = lane&15, row = (lane>>4)*4 + reg
  const int cn0 = lane & 15;
  const int rm0 = (lane >> 4) * 4;
#pragma unroll
  for (int n = 0; n < 4; ++n) {
    const int ng = bn * 128 + wc * 64 + n * 16 + cn0;
    const float bv = bias[ng];
#pragma unroll
    for (int m = 0; m < 4; ++m) {
      const int mg = bm * 128 + wr * 64 + m * 16 + rm0;
#pragma unroll
      for (int r = 0; r < 4; ++r)
        C[(size_t)(mg + r) * 512 + ng] = acc[m][n][r] + bv;
    }
  }
}

// ---------------------------------------------------------------------------
// K2: lane = token. Each wave: 64 tokens of one head. W rows wave-uniform
// (scalar loads). Per-lane softmax; writes wcat hi/lo bf16 + nrm[h][g].
// ---------------------------------------------------------------------------
__global__ __launch_bounds__(256) void k2_route(
    const float* __restrict__ xp, const float* __restrict__ Wsl,
    const float* __restrict__ bsl, const float* __restrict__ Wt1,
    const float* __restrict__ bt1, const float* __restrict__ Wt2,
    const float* __restrict__ bt2, const float* __restrict__ tbias,
    u16* __restrict__ wh, u16* __restrict__ wl, float* __restrict__ nrm)
{
  __shared__ float sbuf[4][64 * 65];
  __shared__ float invbuf[4][64];
  const int lane = threadIdx.x & 63;
  const int wid  = threadIdx.x >> 6;
  const int gw   = blockIdx.x * 4 + wid;
  const int p    = gw * 64 + lane;
  const int h    = p >> 16;
  const int n    = p & 65535;
  const int n0   = (gw * 64) & 65535;

  float x[64];
  const float* xrow = xp + (size_t)n * 512 + h * 64;
#pragma unroll
  for (int q = 0; q < 16; ++q) {
    float4 v = *(const float4*)(xrow + q * 4);
    x[q * 4 + 0] = v.x; x[q * 4 + 1] = v.y;
    x[q * 4 + 2] = v.z; x[q * 4 + 3] = v.w;
  }

  float tc = 0.f;
  for (int g = 0; g < 64; ++g) {
    const float* wr = Wt1 + g * 64;
    float a0 = bt1[g], a1 = 0.f, a2 = 0.f, a3 = 0.f;
#pragma unroll
    for (int q = 0; q < 16; ++q) {
      float4 wv = *(const float4*)(wr + q * 4);
      a0 = fmaf(x[q * 4 + 0], wv.x, a0);
      a1 = fmaf(x[q * 4 + 1], wv.y, a1);
      a2 = fmaf(x[q * 4 + 2], wv.z, a2);
      a3 = fmaf(x[q * 4 + 3], wv.w, a3);
    }
    tc = fmaf(gelu_fast((a0 + a1) + (a2 + a3)), Wt2[g], tc);
  }
  float tval = gelu_fast(tc + bt2[0]) + tbias[h];
  tval = fmaxf(tval, 0.01f);
  const float itval = 1.0f / tval;

  float mx = -3.4e38f;
  for (int g = 0; g < 64; ++g) {
    const float* wr = Wsl + g * 64;
    float a0 = bsl[g], a1 = 0.f, a2 = 0.f, a3 = 0.f;
#pragma unroll
    for (int q = 0; q < 16; ++q) {
      float4 wv = *(const float4*)(wr + q * 4);
      a0 = fmaf(x[q * 4 + 0], wv.x, a0);
      a1 = fmaf(x[q * 4 + 1], wv.y, a1);
      a2 = fmaf(x[q * 4 + 2], wv.z, a2);
      a3 = fmaf(x[q * 4 + 3], wv.w, a3);
    }
    const float lg = (a0 + a1) + (a2 + a3);

    const uint32_t bits = threefry_bits(((uint32_t)p << 6) | (uint32_t)g);
    const float u = __uint_as_float((bits >> 9) | 0x3f800000u) - 1.0f;
    const float gin = -__logf(u + 1e-8f);
    const float gn = -__logf(gin + 1e-8f);

    const float sv = (lg + gn) * itval;
    sbuf[wid][lane * 65 + g] = sv;
    mx = fmaxf(mx, sv);
  }

  float se = 0.f;
  for (int g = 0; g < 64; ++g) {
    const float e = __expf(sbuf[wid][lane * 65 + g] - mx);
    se += e;
    sbuf[wid][lane * 65 + g] = e;
  }
  invbuf[wid][lane] = 1.0f / se;

  float nacc = 0.f;
  for (int t = 0; t < 64; ++t) {
    const float wv = sbuf[wid][t * 65 + lane] * invbuf[wid][t];
    nacc += wv;
    const size_t idx = (size_t)(n0 + t) * 512 + h * 64 + lane;
    const u16 hb = f2bf(wv);
    wh[idx] = hb;
    wl[idx] = f2bf(wv - bf2f(hb));
  }
  atomicAdd(&nrm[h * 64 + lane], nacc);
}

// ---------------------------------------------------------------------------
// K3: tok_num[h,g,d] = sum_n w[n,g]*x[n,d].  Tiled rank-K outer product.
// w reconstructed from hi/lo bf16 planes.
// ---------------------------------------------------------------------------
__global__ __launch_bounds__(256) void k3_pool(
    const float* __restrict__ xp, const u16* __restrict__ wh,
    const u16* __restrict__ wl, float* __restrict__ tok_num)
{
  __shared__ float Xs[64][66];
  __shared__ float Ws[64][66];
  const int h = blockIdx.x >> 5;
  const int chunk = blockIdx.x & 31;
  const int tid = threadIdx.x;
  const int lane = tid & 63;
  const int wid = tid >> 6;
  const int ft = tid & 15;
  const int tk = tid >> 4;
  const int i0 = (lane & 7) * 8;
  const int j0 = (lane >> 3) * 8;

  float acc[8][8];
#pragma unroll
  for (int j = 0; j < 8; ++j)
#pragma unroll
    for (int i = 0; i < 8; ++i) acc[j][i] = 0.f;

  for (int r = 0; r < 32; ++r) {
    const int n0 = chunk * 2048 + r * 64;
    __syncthreads();
#pragma unroll
    for (int b = 0; b < 4; ++b) {
      const int t = tk + b * 16;
      const size_t off = (size_t)(n0 + t) * 512 + h * 64 + ft * 4;
      float4 xv = *(const float4*)(xp + off);
      ushort4 hv = *(const ushort4*)(wh + off);
      ushort4 lv = *(const ushort4*)(wl + off);
      *(float4*)&Xs[t][ft * 4] = xv;
      Ws[t][ft * 4 + 0] = bf2f(hv.x) + bf2f(lv.x);
      Ws[t][ft * 4 + 1] = bf2f(hv.y) + bf2f(lv.y);
      Ws[t][ft * 4 + 2] = bf2f(hv.z) + bf2f(lv.z);
      Ws[t][ft * 4 + 3] = bf2f(hv.w) + bf2f(lv.w);
    }
    __syncthreads();
#pragma unroll 4
    for (int tt = 0; tt < 16; ++tt) {
      const int t = wid * 16 + tt;
      float x8[8], w8[8];
      *(float4*)&x8[0] = *(const float4*)&Xs[t][i0];
      *(float4*)&x8[4] = *(const float4*)&Xs[t][i0 + 4];
      *(float4*)&w8[0] = *(const float4*)&Ws[t][j0];
      *(float4*)&w8[4] = *(const float4*)&Ws[t][j0 + 4];
#pragma unroll
      for (int j = 0; j < 8; ++j)
#pragma unroll
        for (int i = 0; i < 8; ++i)
          acc[j][i] = fmaf(w8[j], x8[i], acc[j][i]);
    }
  }

#pragma unroll
  for (int j = 0; j < 8; ++j)
#pragma unroll
    for (int i = 0; i < 8; ++i)
      atomicAdd(&tok_num[h * 4096 + (j0 + j) * 64 + i0 + i], acc[j][i]);
}

// ---------------------------------------------------------------------------
// K4a: per-head attention over G=64 slice tokens. One block per head.
// ---------------------------------------------------------------------------
__global__ __launch_bounds__(256) void k4_attn(
    const float* __restrict__ tok_num, const float* __restrict__ nrm,
    const float* __restrict__ Wq, const float* __restrict__ Wk,
    const float* __restrict__ Wv, const float* __restrict__ Wo,
    float* __restrict__ o_out)
{
  __shared__ float T[64][65], Abuf[64][65], Bbuf[64][65], Wbuf[64][65], S2[64][65];
  const int h = blockIdx.x;
  const int tid = threadIdx.x;

  for (int e = tid; e < 4096; e += 256) {
    const int g = e >> 6, d = e & 63;
    T[g][d] = tok_num[h * 4096 + e] / (nrm[h * 64 + g] + 1e-5f);
  }
  for (int e = tid; e < 4096; e += 256) Wbuf[e >> 6][e & 63] = Wq[e];
  __syncthreads();

  const int g = tid >> 2, d0 = (tid & 3) * 16;
  float r[16];

#pragma unroll
  for (int j = 0; j < 16; ++j) r[j] = 0.f;
  for (int e = 0; e < 64; ++e) {
    const float tv = T[g][e];
#pragma unroll
    for (int j = 0; j < 16; ++j) r[j] = fmaf(tv, Wbuf[d0 + j][e], r[j]);
  }
#pragma unroll
  for (int j = 0; j < 16; ++j) Abuf[g][d0 + j] = r[j];
  __syncthreads();

  for (int e = tid; e < 4096; e += 256) Wbuf[e >> 6][e & 63] = Wk[e];
  __syncthreads();

#pragma unroll
  for (int j = 0; j < 16; ++j) r[j] = 0.f;
  for (int e = 0; e < 64; ++e) {
    const float tv = T[g][e];
#pragma unroll
    for (int j = 0; j < 16; ++j) r[j] = fmaf(tv, Wbuf[d0 + j][e], r[j]);
  }
#pragma unroll
  for (int j = 0; j < 16; ++j) Bbuf[g][d0 + j] = r[j];
  __syncthreads();

#pragma unroll
  for (int j = 0; j < 16; ++j) r[j] = 0.f;
  for (int e = 0; e < 64; ++e) {
    const float qv = Abuf[g][e] * 0.125f;
#pragma unroll
    for (int j = 0; j < 16; ++j) r[j] = fmaf(qv, Bbuf[d0 + j][e], r[j]);
  }
#pragma unroll
  for (int j = 0; j < 16; ++j) S2[g][d0 + j] = r[j];
  __syncthreads();

  if (tid < 64) {
    float mx = -1e30f;
    for (int j = 0; j < 64; ++j) mx = fmaxf(mx, S2[tid][j]);
    float sum = 0.f;
    for (int j = 0; j < 64; ++j) {
      const float e2 = expf(S2[tid][j] - mx);
      S2[tid][j] = e2;
      sum += e2;
    }
    const float inv = 1.0f / sum;
    for (int j = 0; j < 64; ++j) S2[tid][j] *= inv;
  }
  __syncthreads();

  for (int e = tid; e < 4096; e += 256) Wbuf[e >> 6][e & 63] = Wv[e];
  __syncthreads();

#pragma unroll
  for (int j = 0; j < 16; ++j) r[j] = 0.f;
  for (int e = 0; e < 64; ++e) {
    const float tv = T[g][e];
#pragma unroll
    for (int j = 0; j < 16; ++j) r[j] = fmaf(tv, Wbuf[d0 + j][e], r[j]);
  }
  __syncthreads();
#pragma unroll
  for (int j = 0; j < 16; ++j) Bbuf[g][d0 + j] = r[j];
  __syncthreads();

#pragma unroll
  for (int j = 0; j < 16; ++j) r[j] = 0.f;
  for (int e = 0; e < 64; ++e) {
    const float sv = S2[g][e];
#pragma unroll
    for (int j = 0; j < 16; ++j) r[j] = fmaf(sv, Bbuf[e][d0 + j], r[j]);
  }
  __syncthreads();
#pragma unroll
  for (int j = 0; j < 16; ++j) Abuf[g][d0 + j] = r[j];
  for (int e = tid; e < 4096; e += 256) Wbuf[e >> 6][e & 63] = Wo[e];
  __syncthreads();

#pragma unroll
  for (int j = 0; j < 16; ++j) r[j] = 0.f;
  for (int e = 0; e < 64; ++e) {
    const float ov = Abuf[g][e];
#pragma unroll
    for (int j = 0; j < 16; ++j) r[j] = fmaf(ov, Wbuf[d0 + j][e], r[j]);
  }
#pragma unroll
  for (int j = 0; j < 16; ++j) o_out[h * 4096 + g * 64 + d0 + j] = r[j];
}

// ---------------------------------------------------------------------------
// K4b: M2T[j][hg] = sum_d o[hg][d] * W_out[j][h*64+d]  -> hi/lo bf16 planes
// ---------------------------------------------------------------------------
__global__ __launch_bounds__(256) void k4b_m2(
    const float* __restrict__ o, const float* __restrict__ Wout,
    u16* __restrict__ M2h, u16* __restrict__ M2l)
{
  const int j = blockIdx.x >> 1;
  const int hg = ((blockIdx.x & 1) << 8) + threadIdx.x;
  const int h = hg >> 6;
  const float* orow = &o[hg * 64];
  const float* wrow = &Wout[j * 512 + h * 64];
  float s = 0.f;
#pragma unroll
  for (int d = 0; d < 64; ++d) s = fmaf(orow[d], wrow[d], s);
  const u16 hb = f2bf(s);
  M2h[j * 512 + hg] = hb;
  M2l[j * 512 + hg] = f2bf(s - bf2f(hb));
}

// ---------------------------------------------------------------------------
extern "C" void kernel_launch(void* const* d_in, const int* in_sizes, int n_in,
                              void* d_out, int out_size, void* d_ws, size_t ws_size,
                              hipStream_t stream)
{
  const float* x      = (const float*)d_in[0];
  const float* W_x    = (const float*)d_in[1];
  const float* b_x    = (const float*)d_in[2];
  const float* W_sl   = (const float*)d_in[3];
  const float* b_sl   = (const float*)d_in[4];
  const float* W_t1   = (const float*)d_in[5];
  const float* b_t1   = (const float*)d_in[6];
  const float* W_t2   = (const float*)d_in[7];
  const float* b_t2   = (const float*)d_in[8];
  const float* t_bias = (const float*)d_in[9];
  const float* Wq     = (const float*)d_in[10];
  const float* Wk     = (const float*)d_in[11];
  const float* Wv     = (const float*)d_in[12];
  const float* Wo     = (const float*)d_in[13];
  const float* W_out  = (const float*)d_in[14];
  const float* b_out  = (const float*)d_in[15];

  float* out = (float*)d_out;
  float* xp = out;   // xp lives in d_out; overwritten by final GEMM

  char* ws = (char*)d_ws;
  // region A/B: x hi/lo during GEMM1, then reused as wcat hi/lo
  u16*   Ahi     = (u16*)(ws);                   // 67108864 B
  u16*   Alo     = (u16*)(ws + 67108864);        // 67108864 B
  // small region: Wx hi/lo during GEMM1, then reused as M2T hi/lo
  u16*   Bhi     = (u16*)(ws + 134217728);       // 524288 B
  u16*   Blo     = (u16*)(ws + 134742016);       // 524288 B
  float* tok_num = (float*)(ws + 135266304);     // 131072 B
  float* nrm     = (float*)(ws + 135397376);     // 2048 B
  float* o_buf   = (float*)(ws + 135399424);     // 131072 B
  // total: 135530496 B

  conv_split<<<2048, 256, 0, stream>>>(x, Ahi, Alo, 8388608);
  conv_split<<<256, 256, 0, stream>>>(W_x, Bhi, Blo, 65536);
  gemm_split<<<2048, 256, 0, stream>>>(Ahi, Alo, Bhi, Blo, b_x, xp);

  hipMemsetAsync(tok_num, 0, 133120, stream);  // tok_num + nrm (contiguous)

  k2_route<<<2048, 256, 0, stream>>>(xp, W_sl, b_sl, W_t1, b_t1, W_t2, b_t2,
                                     t_bias, Ahi, Alo, nrm);   // overwrites x-split
  k3_pool<<<256, 256, 0, stream>>>(xp, Ahi, Alo, tok_num);
  k4_attn<<<8, 256, 0, stream>>>(tok_num, nrm, Wq, Wk, Wv, Wo, o_buf);
  k4b_m2<<<1024, 256, 0, stream>>>(o_buf, W_out, Bhi, Blo);    // overwrites Wx-split
  gemm_split<<<2048, 256, 0, stream>>>(Ahi, Alo, Bhi, Blo, b_out, out);
}

// Round 5
// 803.320 us; speedup vs baseline: 2.4803x; 1.1598x over previous
//
#include <hip/hip_runtime.h>
#include <stdint.h>

typedef unsigned short u16;
typedef __bf16 bf16x8 __attribute__((ext_vector_type(8)));
typedef float f32x4 __attribute__((ext_vector_type(4)));

// ---------------------------------------------------------------------------
// EideticPhysicsAttention: N=65536 tokens, HID=512, H=8 heads, D=64, G=64.
//   conv  : split f32 -> (hi,lo) bf16 planes for x and W_x
//   K1    gemm_split : xp = x @ W_x.T + b_x   (split-bf16 MFMA, xp in d_out)
//   K2    k2_route   : MFMA logits+t1 (split-bf16), in-register threefry-
//                      gumbel + temperature + softmax -> wcat hi/lo planes
//   K3    k3_pool    : tok_num[h,g,d] = sum_n x_mid*w ; also nrm[h,g]
//   K4a   k4_attn    : per-head 64-token attention -> o[h,g,d]
//   K4b   k4b_m2     : M2T[j][hg] hi/lo = sum_d o[hg][d]*W_out[j][h*64+d]
//   K5    gemm_split : out = wcat @ M2T.T + b_out      (overwrites d_out)
// ---------------------------------------------------------------------------

__device__ __forceinline__ u16 f2bf(float f) {   // RNE bf16
  uint32_t u = __float_as_uint(f);
  uint32_t r = u + 0x7fffu + ((u >> 16) & 1u);
  return (u16)(r >> 16);
}
__device__ __forceinline__ float bf2f(u16 h) {
  return __uint_as_float(((uint32_t)h) << 16);
}

union BF8 { bf16x8 v; u16 u[8]; uint4 q4; };

__device__ __forceinline__ float gelu_fast(float x) {
  // 0.5*x*(1+tanh(z)) == x / (1 + exp(-2z)),  z = c*(x + 0.044715 x^3)
  const float c = 0.79788456080286535588f;
  float z = c * fmaf(0.044715f, x * x * x, x);
  return x / (1.0f + __expf(-2.0f * z));
}

__device__ __forceinline__ uint32_t rotl32(uint32_t v, int s) {
  return (v << s) | (v >> (32 - s));
}

// JAX threefry2x32, key=(0,1) from jax.random.key(1), partitionable path.
__device__ __forceinline__ uint32_t threefry_bits(uint32_t idx) {
  const uint32_t k0 = 0u, k1 = 1u;
  const uint32_t k2 = 0x1BD11BDAu ^ k0 ^ k1;
  uint32_t x0 = 0u + k0;
  uint32_t x1 = idx + k1;
#define TF_R(r) { x0 += x1; x1 = rotl32(x1, r); x1 ^= x0; }
  TF_R(13) TF_R(15) TF_R(26) TF_R(6)
  x0 += k1; x1 += k2 + 1u;
  TF_R(17) TF_R(29) TF_R(16) TF_R(24)
  x0 += k2; x1 += k0 + 2u;
  TF_R(13) TF_R(15) TF_R(26) TF_R(6)
  x0 += k0; x1 += k1 + 3u;
  TF_R(17) TF_R(29) TF_R(16) TF_R(24)
  x0 += k1; x1 += k2 + 4u;
  TF_R(13) TF_R(15) TF_R(26) TF_R(6)
  x0 += k2; x1 += k0 + 5u;
#undef TF_R
  return x0 ^ x1;
}

__device__ __forceinline__ void gload_lds16(const void* g, void* l) {
  __builtin_amdgcn_global_load_lds(
      (const __attribute__((address_space(1))) void*)g,
      (__attribute__((address_space(3))) void*)l, 16, 0, 0);
}

// ---------------------------------------------------------------------------
// conv_split: f32 -> hi/lo bf16 planes (grid-stride over float4 quads)
// ---------------------------------------------------------------------------
__global__ __launch_bounds__(256) void conv_split(
    const float* __restrict__ in, u16* __restrict__ hi, u16* __restrict__ lo,
    int nq)
{
  for (int i = blockIdx.x * 256 + threadIdx.x; i < nq; i += gridDim.x * 256) {
    float4 v = ((const float4*)in)[i];
    ushort4 h, l;
    h.x = f2bf(v.x); l.x = f2bf(v.x - bf2f(h.x));
    h.y = f2bf(v.y); l.y = f2bf(v.y - bf2f(h.y));
    h.z = f2bf(v.z); l.z = f2bf(v.z - bf2f(h.z));
    h.w = f2bf(v.w); l.w = f2bf(v.w - bf2f(h.w));
    ((ushort4*)hi)[i] = h;
    ((ushort4*)lo)[i] = l;
  }
}

// ---------------------------------------------------------------------------
// gemm_split: C[m][j] = sum_k (Ah+Al)[m][k]*(Bh+Bl)[j][k] + bias[j]
// M=65536, N=512, K=512; 128x128 tile, BK=32, 4 waves, 16x16x32 MFMA.
// ---------------------------------------------------------------------------
__global__ __launch_bounds__(256) void gemm_split(
    const u16* __restrict__ Ah, const u16* __restrict__ Al,
    const u16* __restrict__ Bh, const u16* __restrict__ Bl,
    const float* __restrict__ bias, float* __restrict__ C)
{
  __shared__ u16 lds[4][4096];   // [Ah,Al,Bh,Bl][128 rows * 32 k] = 32 KB
  const int tid = threadIdx.x;
  const int lane = tid & 63;
  const int w = tid >> 6;
  const int bn = blockIdx.x & 3;
  const int bm = blockIdx.x >> 2;
  const int wr = w >> 1, wc = w & 1;

  f32x4 acc[4][4];
#pragma unroll
  for (int m = 0; m < 4; ++m)
#pragma unroll
    for (int n = 0; n < 4; ++n) acc[m][n] = (f32x4){0.f, 0.f, 0.f, 0.f};

  const int srow = lane >> 2;
  const int scol = (lane & 3) * 8;

  for (int kt = 0; kt < 16; ++kt) {
    const int k0 = kt * 32;
    __syncthreads();
#pragma unroll
    for (int i = 0; i < 8; ++i) {
      const int mat = i & 3;
      const int rb = w * 2 + (i >> 2);
      const int row = rb * 16 + srow;
      const u16* base = (mat == 0) ? Ah : (mat == 1) ? Al
                       : (mat == 2) ? Bh : Bl;
      const int tbase = (mat < 2) ? bm * 128 : bn * 128;
      const u16* src = base + (size_t)(tbase + row) * 512 + k0 + scol;
      gload_lds16(src, &lds[mat][rb * 512]);
    }
    __syncthreads();

    bf16x8 ah[4], al[4], bh_[4], bl_[4];
    const int co = (lane >> 4) * 8;
    const int rr = lane & 15;
#pragma unroll
    for (int f = 0; f < 4; ++f) {
      const int ra  = (wr * 64 + f * 16 + rr) * 32 + co;
      const int rb2 = (wc * 64 + f * 16 + rr) * 32 + co;
      ah[f]  = *(const bf16x8*)&lds[0][ra];
      al[f]  = *(const bf16x8*)&lds[1][ra];
      bh_[f] = *(const bf16x8*)&lds[2][rb2];
      bl_[f] = *(const bf16x8*)&lds[3][rb2];
    }
#pragma unroll
    for (int m = 0; m < 4; ++m)
#pragma unroll
      for (int n = 0; n < 4; ++n) {
        acc[m][n] = __builtin_amdgcn_mfma_f32_16x16x32_bf16(ah[m], bh_[n], acc[m][n], 0, 0, 0);
        acc[m][n] = __builtin_amdgcn_mfma_f32_16x16x32_bf16(ah[m], bl_[n], acc[m][n], 0, 0, 0);
        acc[m][n] = __builtin_amdgcn_mfma_f32_16x16x32_bf16(al[m], bh_[n], acc[m][n], 0, 0, 0);
      }
  }

  const int cn0 = lane & 15;
  const int rm0 = (lane >> 4) * 4;
#pragma unroll
  for (int n = 0; n < 4; ++n) {
    const int ng = bn * 128 + wc * 64 + n * 16 + cn0;
    const float bv = bias[ng];
#pragma unroll
    for (int m = 0; m < 4; ++m) {
      const int mg = bm * 128 + wr * 64 + m * 16 + rm0;
#pragma unroll
      for (int r = 0; r < 4; ++r)
        C[(size_t)(mg + r) * 512 + ng] = acc[m][n][r] + bv;
    }
  }
}

// ---------------------------------------------------------------------------
// K2: MFMA routing. Block = 4 waves x 2 tiles x 32 tokens = 256 tokens of one
// head. W_cat=[W_slice;W_t1] staged pre-fragmented (hi/lo) in LDS once.
// Wave computes [32 tok x 128 cols] via 16x16x32 MFMA (3-term split-bf16);
// cols 0..63 = slice logits, 64..127 = t1. Post-processing in registers:
// temperature (gelu->Wt2 dot), threefry-gumbel, per-row softmax across the
// 16-lane group; packed hi|lo u32 LDS transpose -> coalesced plane stores.
// wbuf rows padded to 68 u32 (272 B) so uint4 row reads stay 16B-aligned.
// ---------------------------------------------------------------------------
__global__ __launch_bounds__(256) void k2_route(
    const float* __restrict__ xp, const float* __restrict__ Wsl,
    const float* __restrict__ bsl, const float* __restrict__ Wt1,
    const float* __restrict__ bt1, const float* __restrict__ Wt2,
    const float* __restrict__ bt2, const float* __restrict__ tbias,
    u16* __restrict__ wh, u16* __restrict__ wl)
{
  __shared__ u16 Wf[2][8][2][64][8];      // frag-ordered W planes, 32 KB
  __shared__ uint32_t wbuf[4][32][68];    // per-wave transpose, hi|lo<<16

  const int tid = threadIdx.x;
  const int l = tid & 63, wid = tid >> 6;
  const int l15 = l & 15, q = l >> 4;
  const int h = blockIdx.x >> 8;
  const int chunk = blockIdx.x & 255;

  // ---- stage W fragments (once per block) ----
#pragma unroll
  for (int it = 0; it < 8; ++it) {
    const int slot = tid + it * 256;       // 0..2047
    const int p = slot >> 10;
    const int rest = slot & 1023;
    const int nn = rest >> 7;
    const int kk = (rest >> 6) & 1;
    const int sl = rest & 63;
    const int row = nn * 16 + (sl & 15);
    const int kb = kk * 32 + (sl >> 4) * 8;
    const float* src = (row < 64) ? (Wsl + row * 64 + kb)
                                  : (Wt1 + (row - 64) * 64 + kb);
#pragma unroll
    for (int e = 0; e < 8; ++e) {
      const float v = src[e];
      const u16 hb = f2bf(v);
      Wf[p][nn][kk][sl][e] = (p == 0) ? hb : f2bf(v - bf2f(hb));
    }
  }
  __syncthreads();

  // per-lane column constants (col = j*16 + l15)
  float bslv[4], bt1v[4], wt2v[4];
#pragma unroll
  for (int j = 0; j < 4; ++j) {
    bslv[j] = bsl[j * 16 + l15];
    bt1v[j] = bt1[j * 16 + l15];
    wt2v[j] = Wt2[j * 16 + l15];
  }
  const float bt2v = bt2[0], tbv = tbias[h];

  for (int tile = 0; tile < 2; ++tile) {
    const int n0 = chunk * 256 + tile * 128 + wid * 32;

    // ---- A fragments: xp f32 -> split bf16 in registers ----
    bf16x8 ah[2][2], al[2][2];
#pragma unroll
    for (int m = 0; m < 2; ++m)
#pragma unroll
      for (int kk = 0; kk < 2; ++kk) {
        const float* sp = xp + (size_t)(n0 + m * 16 + l15) * 512 + h * 64
                          + kk * 32 + q * 8;
        float4 v0 = *(const float4*)sp;
        float4 v1 = *(const float4*)(sp + 4);
        float vv[8] = {v0.x, v0.y, v0.z, v0.w, v1.x, v1.y, v1.z, v1.w};
        BF8 hv, lv;
#pragma unroll
        for (int e = 0; e < 8; ++e) {
          const u16 hb = f2bf(vv[e]);
          hv.u[e] = hb;
          lv.u[e] = f2bf(vv[e] - bf2f(hb));
        }
        ah[m][kk] = hv.v; al[m][kk] = lv.v;
      }

    // ---- MFMA: [32 tok] x [128 cols], K=64, 3-term ----
    f32x4 acc[2][8];
#pragma unroll
    for (int m = 0; m < 2; ++m)
#pragma unroll
      for (int n = 0; n < 8; ++n) acc[m][n] = (f32x4){0.f, 0.f, 0.f, 0.f};
#pragma unroll
    for (int kk = 0; kk < 2; ++kk)
#pragma unroll
      for (int nn = 0; nn < 8; ++nn) {
        BF8 whf, wlf;
        whf.q4 = *(const uint4*)&Wf[0][nn][kk][l][0];
        wlf.q4 = *(const uint4*)&Wf[1][nn][kk][l][0];
#pragma unroll
        for (int m = 0; m < 2; ++m) {
          acc[m][nn] = __builtin_amdgcn_mfma_f32_16x16x32_bf16(ah[m][kk], whf.v, acc[m][nn], 0, 0, 0);
          acc[m][nn] = __builtin_amdgcn_mfma_f32_16x16x32_bf16(ah[m][kk], wlf.v, acc[m][nn], 0, 0, 0);
          acc[m][nn] = __builtin_amdgcn_mfma_f32_16x16x32_bf16(al[m][kk], whf.v, acc[m][nn], 0, 0, 0);
        }
      }

    // C layout: token lt = m*16 + q*4 + r ; col = n*16 + l15

    // ---- temperature per (m,r): reduce t1 half across 16-lane group ----
    float itv[2][4];
#pragma unroll
    for (int m = 0; m < 2; ++m)
#pragma unroll
      for (int r = 0; r < 4; ++r) {
        float part = 0.f;
#pragma unroll
        for (int j = 0; j < 4; ++j)
          part += gelu_fast(acc[m][4 + j][r] + bt1v[j]) * wt2v[j];
        part += __shfl_xor(part, 1);
        part += __shfl_xor(part, 2);
        part += __shfl_xor(part, 4);
        part += __shfl_xor(part, 8);
        const float tval = gelu_fast(part + bt2v) + tbv;
        itv[m][r] = 1.0f / fmaxf(tval, 0.01f);
      }

    // ---- logits: bias + threefry-gumbel + /t ----
#pragma unroll
    for (int m = 0; m < 2; ++m) {
      const uint32_t pbase =
          ((uint32_t)((h << 16) | (n0 + m * 16 + q * 4))) << 6;
#pragma unroll
      for (int j = 0; j < 4; ++j) {
        const uint32_t cc = j * 16 + l15;
#pragma unroll
        for (int r = 0; r < 4; ++r) {
          const uint32_t bits = threefry_bits(pbase + ((uint32_t)r << 6) + cc);
          const float u = __uint_as_float((bits >> 9) | 0x3f800000u) - 1.0f;
          const float gin = -__logf(u + 1e-8f);
          const float gn = -__logf(gin + 1e-8f);
          acc[m][j][r] = (acc[m][j][r] + bslv[j] + gn) * itv[m][r];
        }
      }
    }

    // ---- softmax over cols (16-lane group x 4 frags) ----
#pragma unroll
    for (int m = 0; m < 2; ++m)
#pragma unroll
      for (int r = 0; r < 4; ++r) {
        float mx = fmaxf(fmaxf(acc[m][0][r], acc[m][1][r]),
                         fmaxf(acc[m][2][r], acc[m][3][r]));
        mx = fmaxf(mx, __shfl_xor(mx, 1));
        mx = fmaxf(mx, __shfl_xor(mx, 2));
        mx = fmaxf(mx, __shfl_xor(mx, 4));
        mx = fmaxf(mx, __shfl_xor(mx, 8));
        float se = 0.f;
#pragma unroll
        for (int j = 0; j < 4; ++j) {
          const float e = __expf(acc[m][j][r] - mx);
          acc[m][j][r] = e;
          se += e;
        }
        se += __shfl_xor(se, 1);
        se += __shfl_xor(se, 2);
        se += __shfl_xor(se, 4);
        se += __shfl_xor(se, 8);
        const float inv = 1.0f / se;
#pragma unroll
        for (int j = 0; j < 4; ++j) acc[m][j][r] *= inv;
      }

    // ---- pack hi|lo to LDS transpose ----
#pragma unroll
    for (int m = 0; m < 2; ++m)
#pragma unroll
      for (int j = 0; j < 4; ++j)
#pragma unroll
        for (int r = 0; r < 4; ++r) {
          const int lt = m * 16 + q * 4 + r;
          const float wv = acc[m][j][r];
          const u16 hb = f2bf(wv);
          const u16 lb = f2bf(wv - bf2f(hb));
          wbuf[wid][lt][j * 16 + l15] = (uint32_t)hb | ((uint32_t)lb << 16);
        }
    __syncthreads();

    // ---- coalesced plane stores: 32 rows x 16 uint4 = 512 -> 64 lanes x 8 ----
#pragma unroll
    for (int it = 0; it < 8; ++it) {
      const int lt = l >> 1;
      const int gq = (l & 1) * 8 + it;    // 0..15
      const uint4 v = *(const uint4*)&wbuf[wid][lt][gq * 4];
      const uint32_t hp0 = (v.x & 0xffffu) | (v.y << 16);
      const uint32_t hp1 = (v.z & 0xffffu) | (v.w << 16);
      const uint32_t lp0 = (v.x >> 16) | (v.y & 0xffff0000u);
      const uint32_t lp1 = (v.z >> 16) | (v.w & 0xffff0000u);
      const size_t b32 = (size_t)(n0 + lt) * 256 + h * 32 + gq * 2;
      *(uint2*)((uint32_t*)wh + b32) = make_uint2(hp0, hp1);
      *(uint2*)((uint32_t*)wl + b32) = make_uint2(lp0, lp1);
    }
    __syncthreads();
  }
}

// ---------------------------------------------------------------------------
// K3: tok_num[h,g,d] = sum_n w[n,g]*x[n,d] + nrm[h,g] = sum_n w[n,g].
// ---------------------------------------------------------------------------
__global__ __launch_bounds__(256) void k3_pool(
    const float* __restrict__ xp, const u16* __restrict__ wh,
    const u16* __restrict__ wl, float* __restrict__ tok_num,
    float* __restrict__ nrm)
{
  __shared__ float Xs[64][66];
  __shared__ float Ws[64][66];
  const int h = blockIdx.x >> 5;
  const int chunk = blockIdx.x & 31;
  const int tid = threadIdx.x;
  const int lane = tid & 63;
  const int wid = tid >> 6;
  const int ft = tid & 15;
  const int tk = tid >> 4;
  const int i0 = (lane & 7) * 8;
  const int j0 = (lane >> 3) * 8;

  float acc[8][8];
#pragma unroll
  for (int j = 0; j < 8; ++j)
#pragma unroll
    for (int i = 0; i < 8; ++i) acc[j][i] = 0.f;
  float csum[8];
#pragma unroll
  for (int j = 0; j < 8; ++j) csum[j] = 0.f;

  for (int r = 0; r < 32; ++r) {
    const int n0 = chunk * 2048 + r * 64;
    __syncthreads();
#pragma unroll
    for (int b = 0; b < 4; ++b) {
      const int t = tk + b * 16;
      const size_t off = (size_t)(n0 + t) * 512 + h * 64 + ft * 4;
      float4 xv = *(const float4*)(xp + off);
      ushort4 hv = *(const ushort4*)(wh + off);
      ushort4 lv = *(const ushort4*)(wl + off);
      *(float4*)&Xs[t][ft * 4] = xv;
      Ws[t][ft * 4 + 0] = bf2f(hv.x) + bf2f(lv.x);
      Ws[t][ft * 4 + 1] = bf2f(hv.y) + bf2f(lv.y);
      Ws[t][ft * 4 + 2] = bf2f(hv.z) + bf2f(lv.z);
      Ws[t][ft * 4 + 3] = bf2f(hv.w) + bf2f(lv.w);
    }
    __syncthreads();
#pragma unroll 4
    for (int tt = 0; tt < 16; ++tt) {
      const int t = wid * 16 + tt;
      float x8[8], w8[8];
      *(float4*)&x8[0] = *(const float4*)&Xs[t][i0];
      *(float4*)&x8[4] = *(const float4*)&Xs[t][i0 + 4];
      *(float4*)&w8[0] = *(const float4*)&Ws[t][j0];
      *(float4*)&w8[4] = *(const float4*)&Ws[t][j0 + 4];
      if ((lane & 7) == 0) {
#pragma unroll
        for (int j = 0; j < 8; ++j) csum[j] += w8[j];
      }
#pragma unroll
      for (int j = 0; j < 8; ++j)
#pragma unroll
        for (int i = 0; i < 8; ++i)
          acc[j][i] = fmaf(w8[j], x8[i], acc[j][i]);
    }
  }

#pragma unroll
  for (int j = 0; j < 8; ++j)
#pragma unroll
    for (int i = 0; i < 8; ++i)
      atomicAdd(&tok_num[h * 4096 + (j0 + j) * 64 + i0 + i], acc[j][i]);
  if ((lane & 7) == 0) {
#pragma unroll
    for (int j = 0; j < 8; ++j)
      atomicAdd(&nrm[h * 64 + j0 + j], csum[j]);
  }
}

// ---------------------------------------------------------------------------
// K4a: per-head attention over G=64 slice tokens. One block per head.
// ---------------------------------------------------------------------------
__global__ __launch_bounds__(256) void k4_attn(
    const float* __restrict__ tok_num, const float* __restrict__ nrm,
    const float* __restrict__ Wq, const float* __restrict__ Wk,
    const float* __restrict__ Wv, const float* __restrict__ Wo,
    float* __restrict__ o_out)
{
  __shared__ float T[64][65], Abuf[64][65], Bbuf[64][65], Wbuf[64][65], S2[64][65];
  const int h = blockIdx.x;
  const int tid = threadIdx.x;

  for (int e = tid; e < 4096; e += 256) {
    const int g = e >> 6, d = e & 63;
    T[g][d] = tok_num[h * 4096 + e] / (nrm[h * 64 + g] + 1e-5f);
  }
  for (int e = tid; e < 4096; e += 256) Wbuf[e >> 6][e & 63] = Wq[e];
  __syncthreads();

  const int g = tid >> 2, d0 = (tid & 3) * 16;
  float r[16];

#pragma unroll
  for (int j = 0; j < 16; ++j) r[j] = 0.f;
  for (int e = 0; e < 64; ++e) {
    const float tv = T[g][e];
#pragma unroll
    for (int j = 0; j < 16; ++j) r[j] = fmaf(tv, Wbuf[d0 + j][e], r[j]);
  }
#pragma unroll
  for (int j = 0; j < 16; ++j) Abuf[g][d0 + j] = r[j];
  __syncthreads();

  for (int e = tid; e < 4096; e += 256) Wbuf[e >> 6][e & 63] = Wk[e];
  __syncthreads();

#pragma unroll
  for (int j = 0; j < 16; ++j) r[j] = 0.f;
  for (int e = 0; e < 64; ++e) {
    const float tv = T[g][e];
#pragma unroll
    for (int j = 0; j < 16; ++j) r[j] = fmaf(tv, Wbuf[d0 + j][e], r[j]);
  }
#pragma unroll
  for (int j = 0; j < 16; ++j) Bbuf[g][d0 + j] = r[j];
  __syncthreads();

#pragma unroll
  for (int j = 0; j < 16; ++j) r[j] = 0.f;
  for (int e = 0; e < 64; ++e) {
    const float qv = Abuf[g][e] * 0.125f;
#pragma unroll
    for (int j = 0; j < 16; ++j) r[j] = fmaf(qv, Bbuf[d0 + j][e], r[j]);
  }
#pragma unroll
  for (int j = 0; j < 16; ++j) S2[g][d0 + j] = r[j];
  __syncthreads();

  if (tid < 64) {
    float mx = -1e30f;
    for (int j = 0; j < 64; ++j) mx = fmaxf(mx, S2[tid][j]);
    float sum = 0.f;
    for (int j = 0; j < 64; ++j) {
      const float e2 = expf(S2[tid][j] - mx);
      S2[tid][j] = e2;
      sum += e2;
    }
    const float inv = 1.0f / sum;
    for (int j = 0; j < 64; ++j) S2[tid][j] *= inv;
  }
  __syncthreads();

  for (int e = tid; e < 4096; e += 256) Wbuf[e >> 6][e & 63] = Wv[e];
  __syncthreads();

#pragma unroll
  for (int j = 0; j < 16; ++j) r[j] = 0.f;
  for (int e = 0; e < 64; ++e) {
    const float tv = T[g][e];
#pragma unroll
    for (int j = 0; j < 16; ++j) r[j] = fmaf(tv, Wbuf[d0 + j][e], r[j]);
  }
  __syncthreads();
#pragma unroll
  for (int j = 0; j < 16; ++j) Bbuf[g][d0 + j] = r[j];
  __syncthreads();

#pragma unroll
  for (int j = 0; j < 16; ++j) r[j] = 0.f;
  for (int e = 0; e < 64; ++e) {
    const float sv = S2[g][e];
#pragma unroll
    for (int j = 0; j < 16; ++j) r[j] = fmaf(sv, Bbuf[e][d0 + j], r[j]);
  }
  __syncthreads();
#pragma unroll
  for (int j = 0; j < 16; ++j) Abuf[g][d0 + j] = r[j];
  for (int e = tid; e < 4096; e += 256) Wbuf[e >> 6][e & 63] = Wo[e];
  __syncthreads();

#pragma unroll
  for (int j = 0; j < 16; ++j) r[j] = 0.f;
  for (int e = 0; e < 64; ++e) {
    const float ov = Abuf[g][e];
#pragma unroll
    for (int j = 0; j < 16; ++j) r[j] = fmaf(ov, Wbuf[d0 + j][e], r[j]);
  }
#pragma unroll
  for (int j = 0; j < 16; ++j) o_out[h * 4096 + g * 64 + d0 + j] = r[j];
}

// ---------------------------------------------------------------------------
// K4b: M2T[j][hg] = sum_d o[hg][d] * W_out[j][h*64+d]  -> hi/lo bf16 planes
// ---------------------------------------------------------------------------
__global__ __launch_bounds__(256) void k4b_m2(
    const float* __restrict__ o, const float* __restrict__ Wout,
    u16* __restrict__ M2h, u16* __restrict__ M2l)
{
  const int j = blockIdx.x >> 1;
  const int hg = ((blockIdx.x & 1) << 8) + threadIdx.x;
  const int h = hg >> 6;
  const float* orow = &o[hg * 64];
  const float* wrow = &Wout[j * 512 + h * 64];
  float s = 0.f;
#pragma unroll
  for (int d = 0; d < 64; ++d) s = fmaf(orow[d], wrow[d], s);
  const u16 hb = f2bf(s);
  M2h[j * 512 + hg] = hb;
  M2l[j * 512 + hg] = f2bf(s - bf2f(hb));
}

// ---------------------------------------------------------------------------
extern "C" void kernel_launch(void* const* d_in, const int* in_sizes, int n_in,
                              void* d_out, int out_size, void* d_ws, size_t ws_size,
                              hipStream_t stream)
{
  const float* x      = (const float*)d_in[0];
  const float* W_x    = (const float*)d_in[1];
  const float* b_x    = (const float*)d_in[2];
  const float* W_sl   = (const float*)d_in[3];
  const float* b_sl   = (const float*)d_in[4];
  const float* W_t1   = (const float*)d_in[5];
  const float* b_t1   = (const float*)d_in[6];
  const float* W_t2   = (const float*)d_in[7];
  const float* b_t2   = (const float*)d_in[8];
  const float* t_bias = (const float*)d_in[9];
  const float* Wq     = (const float*)d_in[10];
  const float* Wk     = (const float*)d_in[11];
  const float* Wv     = (const float*)d_in[12];
  const float* Wo     = (const float*)d_in[13];
  const float* W_out  = (const float*)d_in[14];
  const float* b_out  = (const float*)d_in[15];

  float* out = (float*)d_out;
  float* xp = out;   // xp lives in d_out; overwritten by final GEMM

  char* ws = (char*)d_ws;
  u16*   Ahi     = (u16*)(ws);                   // x hi, then wcat hi
  u16*   Alo     = (u16*)(ws + 67108864);        // x lo, then wcat lo
  u16*   Bhi     = (u16*)(ws + 134217728);       // Wx hi, then M2T hi
  u16*   Blo     = (u16*)(ws + 134742016);       // Wx lo, then M2T lo
  float* tok_num = (float*)(ws + 135266304);     // 131072 B
  float* nrm     = (float*)(ws + 135397376);     // 2048 B
  float* o_buf   = (float*)(ws + 135399424);     // 131072 B

  conv_split<<<2048, 256, 0, stream>>>(x, Ahi, Alo, 8388608);
  conv_split<<<256, 256, 0, stream>>>(W_x, Bhi, Blo, 65536);
  gemm_split<<<2048, 256, 0, stream>>>(Ahi, Alo, Bhi, Blo, b_x, xp);

  hipMemsetAsync(tok_num, 0, 133120, stream);  // tok_num + nrm (contiguous)

  k2_route<<<2048, 256, 0, stream>>>(xp, W_sl, b_sl, W_t1, b_t1, W_t2, b_t2,
                                     t_bias, Ahi, Alo);        // overwrites x-split
  k3_pool<<<256, 256, 0, stream>>>(xp, Ahi, Alo, tok_num, nrm);
  k4_attn<<<8, 256, 0, stream>>>(tok_num, nrm, Wq, Wk, Wv, Wo, o_buf);
  k4b_m2<<<1024, 256, 0, stream>>>(o_buf, W_out, Bhi, Blo);    // overwrites Wx-split
  gemm_split<<<2048, 256, 0, stream>>>(Ahi, Alo, Bhi, Blo, b_out, out);
}

// Round 6
// 749.839 us; speedup vs baseline: 2.6572x; 1.0713x over previous
//
#include <hip/hip_runtime.h>
#include <stdint.h>

typedef unsigned short u16;
typedef __bf16 bf16x8 __attribute__((ext_vector_type(8)));
typedef float f32x4 __attribute__((ext_vector_type(4)));

// ---------------------------------------------------------------------------
// EideticPhysicsAttention: N=65536 tokens, HID=512, H=8 heads, D=64, G=64.
//   conv  : split f32 -> (hi,lo) bf16 planes for x and W_x
//   K1    gemm_split : xp = x @ W_x.T + b_x   (split-bf16 MFMA, xp in d_out)
//   K2    k2_route   : MFMA logits+t1 (split-bf16), in-register threefry-
//                      gumbel + temperature + softmax -> wcat hi/lo planes
//   K3    k3_pool    : tok_num[h,g,d] = sum_n x_mid*w ; also nrm[h,g]
//                      (no-LDS streaming outer product, 1024 blocks)
//   K4a   k4_attn    : per-head 64-token attention -> o[h,g,d]
//   K4b   k4b_m2     : M2T[j][hg] hi/lo = sum_d o[hg][d]*W_out[j][h*64+d]
//   K5    gemm_split : out = wcat @ M2T.T + b_out      (overwrites d_out)
// ---------------------------------------------------------------------------

__device__ __forceinline__ u16 f2bf(float f) {   // RNE bf16
  uint32_t u = __float_as_uint(f);
  uint32_t r = u + 0x7fffu + ((u >> 16) & 1u);
  return (u16)(r >> 16);
}
__device__ __forceinline__ float bf2f(u16 h) {
  return __uint_as_float(((uint32_t)h) << 16);
}

union BF8 { bf16x8 v; u16 u[8]; uint4 q4; };

__device__ __forceinline__ float gelu_fast(float x) {
  // 0.5*x*(1+tanh(z)) == x / (1 + exp(-2z)),  z = c*(x + 0.044715 x^3)
  const float c = 0.79788456080286535588f;
  float z = c * fmaf(0.044715f, x * x * x, x);
  return x / (1.0f + __expf(-2.0f * z));
}

__device__ __forceinline__ uint32_t rotl32(uint32_t v, int s) {
  return (v << s) | (v >> (32 - s));
}

// JAX threefry2x32, key=(0,1) from jax.random.key(1), partitionable path.
__device__ __forceinline__ uint32_t threefry_bits(uint32_t idx) {
  const uint32_t k0 = 0u, k1 = 1u;
  const uint32_t k2 = 0x1BD11BDAu ^ k0 ^ k1;
  uint32_t x0 = 0u + k0;
  uint32_t x1 = idx + k1;
#define TF_R(r) { x0 += x1; x1 = rotl32(x1, r); x1 ^= x0; }
  TF_R(13) TF_R(15) TF_R(26) TF_R(6)
  x0 += k1; x1 += k2 + 1u;
  TF_R(17) TF_R(29) TF_R(16) TF_R(24)
  x0 += k2; x1 += k0 + 2u;
  TF_R(13) TF_R(15) TF_R(26) TF_R(6)
  x0 += k0; x1 += k1 + 3u;
  TF_R(17) TF_R(29) TF_R(16) TF_R(24)
  x0 += k1; x1 += k2 + 4u;
  TF_R(13) TF_R(15) TF_R(26) TF_R(6)
  x0 += k2; x1 += k0 + 5u;
#undef TF_R
  return x0 ^ x1;
}

__device__ __forceinline__ void gload_lds16(const void* g, void* l) {
  __builtin_amdgcn_global_load_lds(
      (const __attribute__((address_space(1))) void*)g,
      (__attribute__((address_space(3))) void*)l, 16, 0, 0);
}

// ---------------------------------------------------------------------------
// conv_split: f32 -> hi/lo bf16 planes (grid-stride over float4 quads)
// ---------------------------------------------------------------------------
__global__ __launch_bounds__(256) void conv_split(
    const float* __restrict__ in, u16* __restrict__ hi, u16* __restrict__ lo,
    int nq)
{
  for (int i = blockIdx.x * 256 + threadIdx.x; i < nq; i += gridDim.x * 256) {
    float4 v = ((const float4*)in)[i];
    ushort4 h, l;
    h.x = f2bf(v.x); l.x = f2bf(v.x - bf2f(h.x));
    h.y = f2bf(v.y); l.y = f2bf(v.y - bf2f(h.y));
    h.z = f2bf(v.z); l.z = f2bf(v.z - bf2f(h.z));
    h.w = f2bf(v.w); l.w = f2bf(v.w - bf2f(h.w));
    ((ushort4*)hi)[i] = h;
    ((ushort4*)lo)[i] = l;
  }
}

// ---------------------------------------------------------------------------
// gemm_split: C[m][j] = sum_k (Ah+Al)[m][k]*(Bh+Bl)[j][k] + bias[j]
// M=65536, N=512, K=512; 128x128 tile, BK=32, 4 waves, 16x16x32 MFMA.
// ---------------------------------------------------------------------------
__global__ __launch_bounds__(256) void gemm_split(
    const u16* __restrict__ Ah, const u16* __restrict__ Al,
    const u16* __restrict__ Bh, const u16* __restrict__ Bl,
    const float* __restrict__ bias, float* __restrict__ C)
{
  __shared__ u16 lds[4][4096];   // [Ah,Al,Bh,Bl][128 rows * 32 k] = 32 KB
  const int tid = threadIdx.x;
  const int lane = tid & 63;
  const int w = tid >> 6;
  const int bn = blockIdx.x & 3;
  const int bm = blockIdx.x >> 2;
  const int wr = w >> 1, wc = w & 1;

  f32x4 acc[4][4];
#pragma unroll
  for (int m = 0; m < 4; ++m)
#pragma unroll
    for (int n = 0; n < 4; ++n) acc[m][n] = (f32x4){0.f, 0.f, 0.f, 0.f};

  const int srow = lane >> 2;
  const int scol = (lane & 3) * 8;

  for (int kt = 0; kt < 16; ++kt) {
    const int k0 = kt * 32;
    __syncthreads();
#pragma unroll
    for (int i = 0; i < 8; ++i) {
      const int mat = i & 3;
      const int rb = w * 2 + (i >> 2);
      const int row = rb * 16 + srow;
      const u16* base = (mat == 0) ? Ah : (mat == 1) ? Al
                       : (mat == 2) ? Bh : Bl;
      const int tbase = (mat < 2) ? bm * 128 : bn * 128;
      const u16* src = base + (size_t)(tbase + row) * 512 + k0 + scol;
      gload_lds16(src, &lds[mat][rb * 512]);
    }
    __syncthreads();

    bf16x8 ah[4], al[4], bh_[4], bl_[4];
    const int co = (lane >> 4) * 8;
    const int rr = lane & 15;
#pragma unroll
    for (int f = 0; f < 4; ++f) {
      const int ra  = (wr * 64 + f * 16 + rr) * 32 + co;
      const int rb2 = (wc * 64 + f * 16 + rr) * 32 + co;
      ah[f]  = *(const bf16x8*)&lds[0][ra];
      al[f]  = *(const bf16x8*)&lds[1][ra];
      bh_[f] = *(const bf16x8*)&lds[2][rb2];
      bl_[f] = *(const bf16x8*)&lds[3][rb2];
    }
#pragma unroll
    for (int m = 0; m < 4; ++m)
#pragma unroll
      for (int n = 0; n < 4; ++n) {
        acc[m][n] = __builtin_amdgcn_mfma_f32_16x16x32_bf16(ah[m], bh_[n], acc[m][n], 0, 0, 0);
        acc[m][n] = __builtin_amdgcn_mfma_f32_16x16x32_bf16(ah[m], bl_[n], acc[m][n], 0, 0, 0);
        acc[m][n] = __builtin_amdgcn_mfma_f32_16x16x32_bf16(al[m], bh_[n], acc[m][n], 0, 0, 0);
      }
  }

  const int cn0 = lane & 15;
  const int rm0 = (lane >> 4) * 4;
#pragma unroll
  for (int n = 0; n < 4; ++n) {
    const int ng = bn * 128 + wc * 64 + n * 16 + cn0;
    const float bv = bias[ng];
#pragma unroll
    for (int m = 0; m < 4; ++m) {
      const int mg = bm * 128 + wr * 64 + m * 16 + rm0;
#pragma unroll
      for (int r = 0; r < 4; ++r)
        C[(size_t)(mg + r) * 512 + ng] = acc[m][n][r] + bv;
    }
  }
}

// ---------------------------------------------------------------------------
// K2: MFMA routing. Block = 4 waves x 2 tiles x 32 tokens = 256 tokens of one
// head. W_cat=[W_slice;W_t1] staged pre-fragmented (hi/lo) in LDS once.
// ---------------------------------------------------------------------------
__global__ __launch_bounds__(256) void k2_route(
    const float* __restrict__ xp, const float* __restrict__ Wsl,
    const float* __restrict__ bsl, const float* __restrict__ Wt1,
    const float* __restrict__ bt1, const float* __restrict__ Wt2,
    const float* __restrict__ bt2, const float* __restrict__ tbias,
    u16* __restrict__ wh, u16* __restrict__ wl)
{
  __shared__ u16 Wf[2][8][2][64][8];      // frag-ordered W planes, 32 KB
  __shared__ uint32_t wbuf[4][32][68];    // per-wave transpose, hi|lo<<16

  const int tid = threadIdx.x;
  const int l = tid & 63, wid = tid >> 6;
  const int l15 = l & 15, q = l >> 4;
  const int h = blockIdx.x >> 8;
  const int chunk = blockIdx.x & 255;

  // ---- stage W fragments (once per block) ----
#pragma unroll
  for (int it = 0; it < 8; ++it) {
    const int slot = tid + it * 256;       // 0..2047
    const int p = slot >> 10;
    const int rest = slot & 1023;
    const int nn = rest >> 7;
    const int kk = (rest >> 6) & 1;
    const int sl = rest & 63;
    const int row = nn * 16 + (sl & 15);
    const int kb = kk * 32 + (sl >> 4) * 8;
    const float* src = (row < 64) ? (Wsl + row * 64 + kb)
                                  : (Wt1 + (row - 64) * 64 + kb);
#pragma unroll
    for (int e = 0; e < 8; ++e) {
      const float v = src[e];
      const u16 hb = f2bf(v);
      Wf[p][nn][kk][sl][e] = (p == 0) ? hb : f2bf(v - bf2f(hb));
    }
  }
  __syncthreads();

  // per-lane column constants (col = j*16 + l15)
  float bslv[4], bt1v[4], wt2v[4];
#pragma unroll
  for (int j = 0; j < 4; ++j) {
    bslv[j] = bsl[j * 16 + l15];
    bt1v[j] = bt1[j * 16 + l15];
    wt2v[j] = Wt2[j * 16 + l15];
  }
  const float bt2v = bt2[0], tbv = tbias[h];

  for (int tile = 0; tile < 2; ++tile) {
    const int n0 = chunk * 256 + tile * 128 + wid * 32;

    // ---- A fragments: xp f32 -> split bf16 in registers ----
    bf16x8 ah[2][2], al[2][2];
#pragma unroll
    for (int m = 0; m < 2; ++m)
#pragma unroll
      for (int kk = 0; kk < 2; ++kk) {
        const float* sp = xp + (size_t)(n0 + m * 16 + l15) * 512 + h * 64
                          + kk * 32 + q * 8;
        float4 v0 = *(const float4*)sp;
        float4 v1 = *(const float4*)(sp + 4);
        float vv[8] = {v0.x, v0.y, v0.z, v0.w, v1.x, v1.y, v1.z, v1.w};
        BF8 hv, lv;
#pragma unroll
        for (int e = 0; e < 8; ++e) {
          const u16 hb = f2bf(vv[e]);
          hv.u[e] = hb;
          lv.u[e] = f2bf(vv[e] - bf2f(hb));
        }
        ah[m][kk] = hv.v; al[m][kk] = lv.v;
      }

    // ---- MFMA: [32 tok] x [128 cols], K=64, 3-term ----
    f32x4 acc[2][8];
#pragma unroll
    for (int m = 0; m < 2; ++m)
#pragma unroll
      for (int n = 0; n < 8; ++n) acc[m][n] = (f32x4){0.f, 0.f, 0.f, 0.f};
#pragma unroll
    for (int kk = 0; kk < 2; ++kk)
#pragma unroll
      for (int nn = 0; nn < 8; ++nn) {
        BF8 whf, wlf;
        whf.q4 = *(const uint4*)&Wf[0][nn][kk][l][0];
        wlf.q4 = *(const uint4*)&Wf[1][nn][kk][l][0];
#pragma unroll
        for (int m = 0; m < 2; ++m) {
          acc[m][nn] = __builtin_amdgcn_mfma_f32_16x16x32_bf16(ah[m][kk], whf.v, acc[m][nn], 0, 0, 0);
          acc[m][nn] = __builtin_amdgcn_mfma_f32_16x16x32_bf16(ah[m][kk], wlf.v, acc[m][nn], 0, 0, 0);
          acc[m][nn] = __builtin_amdgcn_mfma_f32_16x16x32_bf16(al[m][kk], whf.v, acc[m][nn], 0, 0, 0);
        }
      }

    // C layout: token lt = m*16 + q*4 + r ; col = n*16 + l15

    // ---- temperature per (m,r): reduce t1 half across 16-lane group ----
    float itv[2][4];
#pragma unroll
    for (int m = 0; m < 2; ++m)
#pragma unroll
      for (int r = 0; r < 4; ++r) {
        float part = 0.f;
#pragma unroll
        for (int j = 0; j < 4; ++j)
          part += gelu_fast(acc[m][4 + j][r] + bt1v[j]) * wt2v[j];
        part += __shfl_xor(part, 1);
        part += __shfl_xor(part, 2);
        part += __shfl_xor(part, 4);
        part += __shfl_xor(part, 8);
        const float tval = gelu_fast(part + bt2v) + tbv;
        itv[m][r] = 1.0f / fmaxf(tval, 0.01f);
      }

    // ---- logits: bias + threefry-gumbel + /t ----
#pragma unroll
    for (int m = 0; m < 2; ++m) {
      const uint32_t pbase =
          ((uint32_t)((h << 16) | (n0 + m * 16 + q * 4))) << 6;
#pragma unroll
      for (int j = 0; j < 4; ++j) {
        const uint32_t cc = j * 16 + l15;
#pragma unroll
        for (int r = 0; r < 4; ++r) {
          const uint32_t bits = threefry_bits(pbase + ((uint32_t)r << 6) + cc);
          const float u = __uint_as_float((bits >> 9) | 0x3f800000u) - 1.0f;
          const float gin = -__logf(u + 1e-8f);
          const float gn = -__logf(gin + 1e-8f);
          acc[m][j][r] = (acc[m][j][r] + bslv[j] + gn) * itv[m][r];
        }
      }
    }

    // ---- softmax over cols (16-lane group x 4 frags) ----
#pragma unroll
    for (int m = 0; m < 2; ++m)
#pragma unroll
      for (int r = 0; r < 4; ++r) {
        float mx = fmaxf(fmaxf(acc[m][0][r], acc[m][1][r]),
                         fmaxf(acc[m][2][r], acc[m][3][r]));
        mx = fmaxf(mx, __shfl_xor(mx, 1));
        mx = fmaxf(mx, __shfl_xor(mx, 2));
        mx = fmaxf(mx, __shfl_xor(mx, 4));
        mx = fmaxf(mx, __shfl_xor(mx, 8));
        float se = 0.f;
#pragma unroll
        for (int j = 0; j < 4; ++j) {
          const float e = __expf(acc[m][j][r] - mx);
          acc[m][j][r] = e;
          se += e;
        }
        se += __shfl_xor(se, 1);
        se += __shfl_xor(se, 2);
        se += __shfl_xor(se, 4);
        se += __shfl_xor(se, 8);
        const float inv = 1.0f / se;
#pragma unroll
        for (int j = 0; j < 4; ++j) acc[m][j][r] *= inv;
      }

    // ---- pack hi|lo to LDS transpose ----
#pragma unroll
    for (int m = 0; m < 2; ++m)
#pragma unroll
      for (int j = 0; j < 4; ++j)
#pragma unroll
        for (int r = 0; r < 4; ++r) {
          const int lt = m * 16 + q * 4 + r;
          const float wv = acc[m][j][r];
          const u16 hb = f2bf(wv);
          const u16 lb = f2bf(wv - bf2f(hb));
          wbuf[wid][lt][j * 16 + l15] = (uint32_t)hb | ((uint32_t)lb << 16);
        }
    __syncthreads();

    // ---- coalesced plane stores: 32 rows x 16 uint4 = 512 -> 64 lanes x 8 ----
#pragma unroll
    for (int it = 0; it < 8; ++it) {
      const int lt = l >> 1;
      const int gq = (l & 1) * 8 + it;    // 0..15
      const uint4 v = *(const uint4*)&wbuf[wid][lt][gq * 4];
      const uint32_t hp0 = (v.x & 0xffffu) | (v.y << 16);
      const uint32_t hp1 = (v.z & 0xffffu) | (v.w << 16);
      const uint32_t lp0 = (v.x >> 16) | (v.y & 0xffff0000u);
      const uint32_t lp1 = (v.z >> 16) | (v.w & 0xffff0000u);
      const size_t b32 = (size_t)(n0 + lt) * 256 + h * 32 + gq * 2;
      *(uint2*)((uint32_t*)wh + b32) = make_uint2(hp0, hp1);
      *(uint2*)((uint32_t*)wl + b32) = make_uint2(lp0, lp1);
    }
    __syncthreads();
  }
}

// ---------------------------------------------------------------------------
// K3: tok_num[h,g,d] = sum_n w[n,g]*x[n,d] ; nrm[h,g] = sum_n w[n,g].
// No-LDS streaming outer product. Grid = 8 heads x 128 chunks (512 tokens);
// 4 waves x 128 tokens each, lane owns an 8x8 (g,d) patch in registers.
// Cross-wave reduce: sequential LDS accumulate with XOR-swizzled columns
// (col = i0 | (i ^ jq)) -> every reduce instruction spans 32 banks 2-way.
// ---------------------------------------------------------------------------
__global__ __launch_bounds__(256) void k3_pool(
    const float* __restrict__ xp, const u16* __restrict__ wh,
    const u16* __restrict__ wl, float* __restrict__ tok_num,
    float* __restrict__ nrm)
{
  __shared__ float red[64][65];
  __shared__ float redn[64];
  const int h = blockIdx.x >> 7;
  const int chunk = blockIdx.x & 127;
  const int lane = threadIdx.x & 63;
  const int wid = threadIdx.x >> 6;
  const int i0 = (lane & 7) * 8;   // d block
  const int j0 = (lane >> 3) * 8;  // g block
  const int jq = lane >> 3;

  float acc[8][8];
#pragma unroll
  for (int j = 0; j < 8; ++j)
#pragma unroll
    for (int i = 0; i < 8; ++i) acc[j][i] = 0.f;
  float csum[8];
#pragma unroll
  for (int j = 0; j < 8; ++j) csum[j] = 0.f;

  const int n0 = chunk * 512 + wid * 128;
#pragma unroll 2
  for (int t = 0; t < 128; ++t) {
    const size_t base = (size_t)(n0 + t) * 512 + h * 64;
    const float4 x0 = *(const float4*)(xp + base + i0);
    const float4 x1 = *(const float4*)(xp + base + i0 + 4);
    const ushort4 h0 = *(const ushort4*)(wh + base + j0);
    const ushort4 h1 = *(const ushort4*)(wh + base + j0 + 4);
    const ushort4 l0 = *(const ushort4*)(wl + base + j0);
    const ushort4 l1 = *(const ushort4*)(wl + base + j0 + 4);
    const float x8[8] = {x0.x, x0.y, x0.z, x0.w, x1.x, x1.y, x1.z, x1.w};
    const float w8[8] = {
        bf2f(h0.x) + bf2f(l0.x), bf2f(h0.y) + bf2f(l0.y),
        bf2f(h0.z) + bf2f(l0.z), bf2f(h0.w) + bf2f(l0.w),
        bf2f(h1.x) + bf2f(l1.x), bf2f(h1.y) + bf2f(l1.y),
        bf2f(h1.z) + bf2f(l1.z), bf2f(h1.w) + bf2f(l1.w)};
#pragma unroll
    for (int j = 0; j < 8; ++j) csum[j] += w8[j];
#pragma unroll
    for (int j = 0; j < 8; ++j)
#pragma unroll
      for (int i = 0; i < 8; ++i)
        acc[j][i] = fmaf(w8[j], x8[i], acc[j][i]);
  }

  // sequential cross-wave reduce (swizzled: bank = full-rank in lane)
  for (int w = 0; w < 4; ++w) {
    if (wid == w) {
      if (w == 0) {
#pragma unroll
        for (int j = 0; j < 8; ++j)
#pragma unroll
          for (int i = 0; i < 8; ++i)
            red[j0 + j][i0 | (i ^ jq)] = acc[j][i];
        if ((lane & 7) == 0) {
#pragma unroll
          for (int j = 0; j < 8; ++j) redn[j0 + j] = csum[j];
        }
      } else {
#pragma unroll
        for (int j = 0; j < 8; ++j)
#pragma unroll
          for (int i = 0; i < 8; ++i)
            red[j0 + j][i0 | (i ^ jq)] += acc[j][i];
        if ((lane & 7) == 0) {
#pragma unroll
          for (int j = 0; j < 8; ++j) redn[j0 + j] += csum[j];
        }
      }
    }
    __syncthreads();
  }

  for (int e = threadIdx.x; e < 4096; e += 256) {
    const int g = e >> 6, d = e & 63;
    const int col = (d & 56) | ((d & 7) ^ (g >> 3));
    atomicAdd(&tok_num[h * 4096 + e], red[g][col]);
  }
  if (threadIdx.x < 64)
    atomicAdd(&nrm[h * 64 + threadIdx.x], redn[threadIdx.x]);
}

// ---------------------------------------------------------------------------
// K4a: per-head attention over G=64 slice tokens. One block per head.
// ---------------------------------------------------------------------------
__global__ __launch_bounds__(256) void k4_attn(
    const float* __restrict__ tok_num, const float* __restrict__ nrm,
    const float* __restrict__ Wq, const float* __restrict__ Wk,
    const float* __restrict__ Wv, const float* __restrict__ Wo,
    float* __restrict__ o_out)
{
  __shared__ float T[64][65], Abuf[64][65], Bbuf[64][65], Wbuf[64][65], S2[64][65];
  const int h = blockIdx.x;
  const int tid = threadIdx.x;

  for (int e = tid; e < 4096; e += 256) {
    const int g = e >> 6, d = e & 63;
    T[g][d] = tok_num[h * 4096 + e] / (nrm[h * 64 + g] + 1e-5f);
  }
  for (int e = tid; e < 4096; e += 256) Wbuf[e >> 6][e & 63] = Wq[e];
  __syncthreads();

  const int g = tid >> 2, d0 = (tid & 3) * 16;
  float r[16];

#pragma unroll
  for (int j = 0; j < 16; ++j) r[j] = 0.f;
  for (int e = 0; e < 64; ++e) {
    const float tv = T[g][e];
#pragma unroll
    for (int j = 0; j < 16; ++j) r[j] = fmaf(tv, Wbuf[d0 + j][e], r[j]);
  }
#pragma unroll
  for (int j = 0; j < 16; ++j) Abuf[g][d0 + j] = r[j];
  __syncthreads();

  for (int e = tid; e < 4096; e += 256) Wbuf[e >> 6][e & 63] = Wk[e];
  __syncthreads();

#pragma unroll
  for (int j = 0; j < 16; ++j) r[j] = 0.f;
  for (int e = 0; e < 64; ++e) {
    const float tv = T[g][e];
#pragma unroll
    for (int j = 0; j < 16; ++j) r[j] = fmaf(tv, Wbuf[d0 + j][e], r[j]);
  }
#pragma unroll
  for (int j = 0; j < 16; ++j) Bbuf[g][d0 + j] = r[j];
  __syncthreads();

#pragma unroll
  for (int j = 0; j < 16; ++j) r[j] = 0.f;
  for (int e = 0; e < 64; ++e) {
    const float qv = Abuf[g][e] * 0.125f;
#pragma unroll
    for (int j = 0; j < 16; ++j) r[j] = fmaf(qv, Bbuf[d0 + j][e], r[j]);
  }
#pragma unroll
  for (int j = 0; j < 16; ++j) S2[g][d0 + j] = r[j];
  __syncthreads();

  if (tid < 64) {
    float mx = -1e30f;
    for (int j = 0; j < 64; ++j) mx = fmaxf(mx, S2[tid][j]);
    float sum = 0.f;
    for (int j = 0; j < 64; ++j) {
      const float e2 = expf(S2[tid][j] - mx);
      S2[tid][j] = e2;
      sum += e2;
    }
    const float inv = 1.0f / sum;
    for (int j = 0; j < 64; ++j) S2[tid][j] *= inv;
  }
  __syncthreads();

  for (int e = tid; e < 4096; e += 256) Wbuf[e >> 6][e & 63] = Wv[e];
  __syncthreads();

#pragma unroll
  for (int j = 0; j < 16; ++j) r[j] = 0.f;
  for (int e = 0; e < 64; ++e) {
    const float tv = T[g][e];
#pragma unroll
    for (int j = 0; j < 16; ++j) r[j] = fmaf(tv, Wbuf[d0 + j][e], r[j]);
  }
  __syncthreads();
#pragma unroll
  for (int j = 0; j < 16; ++j) Bbuf[g][d0 + j] = r[j];
  __syncthreads();

#pragma unroll
  for (int j = 0; j < 16; ++j) r[j] = 0.f;
  for (int e = 0; e < 64; ++e) {
    const float sv = S2[g][e];
#pragma unroll
    for (int j = 0; j < 16; ++j) r[j] = fmaf(sv, Bbuf[e][d0 + j], r[j]);
  }
  __syncthreads();
#pragma unroll
  for (int j = 0; j < 16; ++j) Abuf[g][d0 + j] = r[j];
  for (int e = tid; e < 4096; e += 256) Wbuf[e >> 6][e & 63] = Wo[e];
  __syncthreads();

#pragma unroll
  for (int j = 0; j < 16; ++j) r[j] = 0.f;
  for (int e = 0; e < 64; ++e) {
    const float ov = Abuf[g][e];
#pragma unroll
    for (int j = 0; j < 16; ++j) r[j] = fmaf(ov, Wbuf[d0 + j][e], r[j]);
  }
#pragma unroll
  for (int j = 0; j < 16; ++j) o_out[h * 4096 + g * 64 + d0 + j] = r[j];
}

// ---------------------------------------------------------------------------
// K4b: M2T[j][hg] = sum_d o[hg][d] * W_out[j][h*64+d]  -> hi/lo bf16 planes
// ---------------------------------------------------------------------------
__global__ __launch_bounds__(256) void k4b_m2(
    const float* __restrict__ o, const float* __restrict__ Wout,
    u16* __restrict__ M2h, u16* __restrict__ M2l)
{
  const int j = blockIdx.x >> 1;
  const int hg = ((blockIdx.x & 1) << 8) + threadIdx.x;
  const int h = hg >> 6;
  const float* orow = &o[hg * 64];
  const float* wrow = &Wout[j * 512 + h * 64];
  float s = 0.f;
#pragma unroll
  for (int d = 0; d < 64; ++d) s = fmaf(orow[d], wrow[d], s);
  const u16 hb = f2bf(s);
  M2h[j * 512 + hg] = hb;
  M2l[j * 512 + hg] = f2bf(s - bf2f(hb));
}

// ---------------------------------------------------------------------------
extern "C" void kernel_launch(void* const* d_in, const int* in_sizes, int n_in,
                              void* d_out, int out_size, void* d_ws, size_t ws_size,
                              hipStream_t stream)
{
  const float* x      = (const float*)d_in[0];
  const float* W_x    = (const float*)d_in[1];
  const float* b_x    = (const float*)d_in[2];
  const float* W_sl   = (const float*)d_in[3];
  const float* b_sl   = (const float*)d_in[4];
  const float* W_t1   = (const float*)d_in[5];
  const float* b_t1   = (const float*)d_in[6];
  const float* W_t2   = (const float*)d_in[7];
  const float* b_t2   = (const float*)d_in[8];
  const float* t_bias = (const float*)d_in[9];
  const float* Wq     = (const float*)d_in[10];
  const float* Wk     = (const float*)d_in[11];
  const float* Wv     = (const float*)d_in[12];
  const float* Wo     = (const float*)d_in[13];
  const float* W_out  = (const float*)d_in[14];
  const float* b_out  = (const float*)d_in[15];

  float* out = (float*)d_out;
  float* xp = out;   // xp lives in d_out; overwritten by final GEMM

  char* ws = (char*)d_ws;
  u16*   Ahi     = (u16*)(ws);                   // x hi, then wcat hi
  u16*   Alo     = (u16*)(ws + 67108864);        // x lo, then wcat lo
  u16*   Bhi     = (u16*)(ws + 134217728);       // Wx hi, then M2T hi
  u16*   Blo     = (u16*)(ws + 134742016);       // Wx lo, then M2T lo
  float* tok_num = (float*)(ws + 135266304);     // 131072 B
  float* nrm     = (float*)(ws + 135397376);     // 2048 B
  float* o_buf   = (float*)(ws + 135399424);     // 131072 B

  conv_split<<<2048, 256, 0, stream>>>(x, Ahi, Alo, 8388608);
  conv_split<<<256, 256, 0, stream>>>(W_x, Bhi, Blo, 65536);
  gemm_split<<<2048, 256, 0, stream>>>(Ahi, Alo, Bhi, Blo, b_x, xp);

  hipMemsetAsync(tok_num, 0, 133120, stream);  // tok_num + nrm (contiguous)

  k2_route<<<2048, 256, 0, stream>>>(xp, W_sl, b_sl, W_t1, b_t1, W_t2, b_t2,
                                     t_bias, Ahi, Alo);        // overwrites x-split
  k3_pool<<<1024, 256, 0, stream>>>(xp, Ahi, Alo, tok_num, nrm);
  k4_attn<<<8, 256, 0, stream>>>(tok_num, nrm, Wq, Wk, Wv, Wo, o_buf);
  k4b_m2<<<1024, 256, 0, stream>>>(o_buf, W_out, Bhi, Blo);    // overwrites Wx-split
  gemm_split<<<2048, 256, 0, stream>>>(Ahi, Alo, Bhi, Blo, b_out, out);
}